// Round 10
// baseline (235.745 us; speedup 1.0000x reference)
//
#include <hip/hip_runtime.h>

// SHGR kNN head: cosine distance, top-16, inverse-distance weighted target average.
// B=2048, N=100000, D=128, T=8, k=16.
//
// Pipeline:
//   1. norm_rows_k: L2-normalize supports & queries -> bf16 (ushort bits) in ws.
//   2. pass1_k: bf16 MFMA (TRANSPOSED: D[support][query] so the 16-support sub
//      reduction is 3 in-reg fmax + 2 shfl); per-(query,16-support sub) max ->
//      cm (global, bf16 down-rounded, packed [q/4][gs][q%4]).
//      Counted-vmcnt pipeline: raw s_barrier + vmcnt(8) so next-chunk
//      global_load_lds stays in flight across the barrier (T3/T4 minimum).
//   3. thr_k: thr[q] = (16th-largest of 6400 sub-maxes) - 0.013 margin.
//      [16th submax <= true 16th score; margin covers bf16 score error
//      (<=2.5e-3 worst case) with 5x slack; E[cands] = 16*exp(41*margin) ~ 27]
//   4. pass2_k: per (qtile,slice) block: find hit subs (stored max >= thr),
//      batch 4 subs -> staged 64-row tile, recompute scores (transposed MFMA),
//      emit scores >= thr to a per-query global list (cap 64). Keeps
//      __syncthreads (divergent emission -> counted vmcnt unsafe here).
//   5. merge_refine_k: per query, exact (f64) refine ALL ~27 candidates,
//      bitonic top-16 -> weights -> gather targets -> out.
//
// NOTE (R7): update_dpp row_ror gave wrong submaxes on gfx950 -> shfl_xor only.

#define NSLICES 80               // 100000/80 = 1250 exactly; grid 1280 = 5 blk/CU
#define CN 64
#define BQ 128
#define NSUB 80                  // subs per slice = 20 chunks * 4
#define NGS (NSLICES * NSUB)     // 6400 subs per query
#define QCAP 64                  // per-query candidate list; E=27, P(>64)~1e-9
#define THR_MARGIN 0.013f

typedef __bf16 bf16x8 __attribute__((ext_vector_type(8)));
typedef float f32x4 __attribute__((ext_vector_type(4)));

__device__ __forceinline__ ushort f2bf_rne(float f) {
  unsigned u = __float_as_uint(f);
  return (ushort)((u + 0x7FFFu + ((u >> 16) & 1u)) >> 16);
}
// round toward -inf in bf16 (stored max <= true max)
__device__ __forceinline__ ushort f2bf_down(float f) {
  unsigned u = __float_as_uint(f);
  return (ushort)((u >> 16) + (u >> 31));
}
__device__ __forceinline__ unsigned bf2key(ushort b) {
  return (unsigned)(b ^ ((b & 0x8000u) ? 0xFFFFu : 0x8000u));
}

// Full-wave bitonic sort, ascending in (v, i) lexicographic.
__device__ __forceinline__ void bitonic64(float& v, unsigned& i, int lane) {
  #pragma unroll
  for (int k = 2; k <= 64; k <<= 1) {
    #pragma unroll
    for (int j = k >> 1; j > 0; j >>= 1) {
      float pv = __shfl_xor(v, j);
      unsigned pi = (unsigned)__shfl_xor((int)i, j);
      bool up = ((lane & k) == 0);
      bool lower = ((lane & j) == 0);
      bool gt = (v > pv) || (v == pv && i > pi);
      bool keep = (up == lower) ? !gt : gt;
      if (!keep) { v = pv; i = pi; }
    }
  }
}

__global__ __launch_bounds__(256) void norm_rows_k(const float* __restrict__ x,
                                                   ushort* __restrict__ xb,
                                                   int nrows) {
  int row = blockIdx.x * 4 + (threadIdx.x >> 6);
  int lane = threadIdx.x & 63;
  if (row >= nrows) return;
  float2 v = *reinterpret_cast<const float2*>(x + (size_t)row * 128 + lane * 2);
  float ss = v.x * v.x + v.y * v.y;
  #pragma unroll
  for (int o = 1; o < 64; o <<= 1) ss += __shfl_xor(ss, o);
  float inv = 1.0f / fmaxf(sqrtf(ss), 1e-12f);
  ushort2 h = make_ushort2(f2bf_rne(v.x * inv), f2bf_rne(v.y * inv));
  *reinterpret_cast<ushort2*>(xb + (size_t)row * 128 + lane * 2) = h;
}

// Stage 64x128 bf16 chunk: linear LDS dest + inverse-swizzled global source.
// Exactly 4 global_load_lds instructions per wave (vmcnt += 4).
__device__ __forceinline__ void stage_lin(const ushort* __restrict__ sn,
                                          ushort* dst, int cb, int s1, int tid) {
  #pragma unroll
  for (int r = 0; r < 4; ++r) {
    int o = (r << 12) + tid * 16;
    int row = o >> 8;
    int dj = (o >> 4) & 15;
    int sj = dj ^ (row & 7);
    int srow = min(cb + row, s1 - 1);
    __builtin_amdgcn_global_load_lds(
        (const unsigned int*)(sn + (size_t)srow * 128 + sj * 8),
        (unsigned int*)(dst + (o >> 1)), 16, 0, 0);
  }
}

// Stage a gathered batch of 4 sub-chunks (16 rows each) from slist.
__device__ __forceinline__ void stage_list(const ushort* __restrict__ sn,
                                           ushort* dst, const ushort* slist_b,
                                           int s0, int s1, int tid) {
  #pragma unroll
  for (int r = 0; r < 4; ++r) {
    int o = (r << 12) + tid * 16;
    int row = o >> 8;
    int dj = (o >> 4) & 15;
    int sj = dj ^ (row & 7);
    int sub = slist_b[row >> 4];
    int lrow = (sub == 0xFFFF) ? 0 : sub * 16 + (row & 15);
    int srow = min(s0 + lrow, s1 - 1);
    __builtin_amdgcn_global_load_lds(
        (const unsigned int*)(sn + (size_t)srow * 128 + sj * 8),
        (unsigned int*)(dst + (o >> 1)), 16, 0, 0);
  }
}

// Pass 1: sub-chunk maxes. 1280 blocks XCD-decoded (10 slices/XCD, 3.2MB L2).
// Transposed MFMA: D[row=support][col=query]; lane holds 4 supports x 1 query.
// Counted-vmcnt pipeline: prefetch loads stay in flight across raw barriers.
__global__ __launch_bounds__(256, 5) void pass1_k(
    const ushort* __restrict__ qn, const ushort* __restrict__ sn,
    ushort* __restrict__ cm, int N) {
  __shared__ ushort st[2][CN * 128];
  const int tid = threadIdx.x;
  const int w = tid >> 6, lane = tid & 63, g = lane >> 4, m = lane & 15;
  const int L = blockIdx.x;             // 1280 = 8 xcd * (16 qtile * 10 slice)
  const int xcd = L & 7, i6 = L >> 3;   // i6 in [0,160)
  const int qtile = i6 & 15;
  const int slice = xcd * 10 + (i6 >> 4);
  const int qbase = qtile * BQ;
  const int SLICE = (N + NSLICES - 1) / NSLICES;  // 1250 (exact)
  const int s0 = slice * SLICE;
  const int s1 = min(N, s0 + SLICE);
  const int nch = (s1 - s0 + CN - 1) / CN;  // 20 uniformly

  stage_lin(sn, &st[0][0], s0, s1, tid);

  // Query fragments (B operand): k = 32*t + 8*g + e, col = m.
  bf16x8 afr[2][4];
  #pragma unroll
  for (int jt = 0; jt < 2; ++jt) {
    int qrow = qbase + w * 32 + jt * 16 + m;
    #pragma unroll
    for (int t = 0; t < 4; ++t)
      afr[jt][t] = *reinterpret_cast<const bf16x8*>(qn + (size_t)qrow * 128 + t * 32 + g * 8);
  }
  // drain chunk-0 loads + afr loads; release all waves
  asm volatile("s_waitcnt vmcnt(0)" ::: "memory");
  __builtin_amdgcn_s_barrier();
  __builtin_amdgcn_sched_barrier(0);

  int buf = 0;
  for (int ch = 0; ch < nch; ++ch) {
    const int cb = s0 + ch * CN;
    const bool has_next = (ch + 1 < nch);
    if (has_next) stage_lin(sn, &st[buf ^ 1][0], cb + CN, s1, tid);  // 4 loads in flight
    const ushort* stc = &st[buf][0];
    const bool lastch = (ch == nch - 1);
    #pragma unroll
    for (int ct = 0; ct < 4; ++ct) {
      const int srow = ct * 16 + m;     // A-operand row = support (lane m)
      f32x4 a0 = {0.f, 0.f, 0.f, 0.f}, a1 = {0.f, 0.f, 0.f, 0.f};
      #pragma unroll
      for (int t = 0; t < 4; ++t) {
        int cj = (4 * t + g) ^ (srow & 7);
        bf16x8 sfr = *reinterpret_cast<const bf16x8*>(&stc[srow * 128 + cj * 8]);
        a0 = __builtin_amdgcn_mfma_f32_16x16x32_bf16(sfr, afr[0][t], a0, 0, 0, 0);
        a1 = __builtin_amdgcn_mfma_f32_16x16x32_bf16(sfr, afr[1][t], a1, 0, 0, 0);
      }
      // mask invalid supports (D rows: support = cb + ct*16 + g*4 + e)
      if (lastch) {
        int si = cb + ct * 16 + g * 4;
        #pragma unroll
        for (int e = 0; e < 4; ++e) {
          if (si + e >= s1) { a0[e] = -3.0e38f; a1[e] = -3.0e38f; }
        }
      }
      // in-register max over 4 supports, then across the 4 g-groups
      float v0 = fmaxf(fmaxf(a0[0], a0[1]), fmaxf(a0[2], a0[3]));
      float v1 = fmaxf(fmaxf(a1[0], a1[1]), fmaxf(a1[2], a1[3]));
      v0 = fmaxf(v0, __shfl_xor(v0, 16));
      v0 = fmaxf(v0, __shfl_xor(v0, 32));
      v1 = fmaxf(v1, __shfl_xor(v1, 16));
      v1 = fmaxf(v1, __shfl_xor(v1, 32));
      // pack 4 queries' bf16 submaxes -> 8B store on lanes (g==0, m%4==0)
      unsigned u0 = (unsigned)f2bf_down(v0);
      unsigned u1 = (unsigned)f2bf_down(v1);
      unsigned w0 = u0 | ((unsigned)__shfl_xor((int)u0, 1) << 16);
      unsigned w1 = u1 | ((unsigned)__shfl_xor((int)u1, 1) << 16);
      unsigned x0 = (unsigned)__shfl_xor((int)w0, 2);
      unsigned x1 = (unsigned)__shfl_xor((int)w1, 2);
      if (g == 0 && (m & 3) == 0) {     // 4 lanes always active -> uniform vmcnt
        int gs = slice * NSUB + ch * 4 + ct;
        int q0 = qbase + w * 32 + m;       // jt=0 queries q0..q0+3 (q0%4==0)
        int q1 = q0 + 16;                  // jt=1
        *reinterpret_cast<uint2*>(cm + ((size_t)(q0 >> 2) * NGS + gs) * 4) =
            make_uint2(w0, x0);
        *reinterpret_cast<uint2*>(cm + ((size_t)(q1 >> 2) * NGS + gs) * 4) =
            make_uint2(w1, x1);
      }
    }
    if (has_next) {
      // vmcnt queue (in-order): [L(next)=4 loads, S(this)=8 stores].
      // vmcnt(8) <=> the 4 prefetch loads retired; stores may stay in flight.
      // Barrier then guarantees ALL waves' prefetch landed and everyone is
      // done reading buf -> next iter may overwrite buf and read buf^1.
      asm volatile("s_waitcnt vmcnt(8)" ::: "memory");
      __builtin_amdgcn_s_barrier();
      __builtin_amdgcn_sched_barrier(0);
    }
    buf ^= 1;
  }
}

// thr[q] = 16th-largest of the 6400 sub-maxes, minus margin. One wave per query.
__global__ __launch_bounds__(64) void thr_k(const ushort* __restrict__ cm,
                                            float* __restrict__ thr) {
  const int q = blockIdx.x, lane = threadIdx.x;
  const size_t base = (size_t)(q >> 2) * NGS * 4 + (q & 3);
  unsigned keys[NGS / 128];
  #pragma unroll
  for (int j = 0; j < NGS / 128; ++j) {
    unsigned k0 = bf2key(cm[base + (size_t)(lane + 128 * j) * 4]);
    unsigned k1 = bf2key(cm[base + (size_t)(lane + 64 + 128 * j) * 4]);
    keys[j] = k0 | (k1 << 16);
  }
  unsigned res = 0;
  for (int b = 15; b >= 0; --b) {
    unsigned t = res | (1u << b);
    int c = 0;
    #pragma unroll
    for (int j = 0; j < NGS / 128; ++j)
      c += (int)((keys[j] & 0xFFFFu) >= t) + (int)((keys[j] >> 16) >= t);
    #pragma unroll
    for (int o = 1; o < 64; o <<= 1) c += __shfl_xor(c, o);
    if (c >= 16) res = t;
  }
  if (lane == 0) {
    ushort b16 = (ushort)((res & 0x8000u) ? (res ^ 0x8000u) : (res ^ 0xFFFFu));
    thr[q] = __uint_as_float((unsigned)b16 << 16) - THR_MARGIN;
  }
}

// Pass 2: visit only hit subs (stored max >= thr), 4 per staged batch.
// Transposed MFMA: lane holds 4 supports x 1 query; thr per lane hoisted.
__global__ __launch_bounds__(256, 4) void pass2_k(
    const ushort* __restrict__ qn, const ushort* __restrict__ sn,
    const ushort* __restrict__ cm, const float* __restrict__ thr,
    unsigned* __restrict__ cnt, float2* __restrict__ candq, int N) {
  __shared__ ushort st[2][CN * 128];
  __shared__ float thr_l[BQ];
  __shared__ unsigned char hit[NSUB];
  __shared__ ushort slist[NSUB + 4];
  __shared__ int nhit_s;

  const int tid = threadIdx.x;
  const int w = tid >> 6, lane = tid & 63, g = lane >> 4, m = lane & 15;
  const int L = blockIdx.x;
  const int xcd = L & 7, i6 = L >> 3;
  const int qtile = i6 & 15;
  const int slice = xcd * 10 + (i6 >> 4);
  const int qbase = qtile * BQ;
  const int SLICE = (N + NSLICES - 1) / NSLICES;
  const int s0 = slice * SLICE;
  const int s1 = min(N, s0 + SLICE);
  const int slen = s1 - s0;

  if (tid < BQ) thr_l[tid] = thr[qbase + tid];
  if (tid < NSUB) hit[tid] = 0;
  __syncthreads();

  // hit scan: thread (q = tid&127, parity = tid>>7) covers s = 2j+parity
  {
    int q = qbase + (tid & 127);
    int sh = tid >> 7;
    float tq = thr_l[tid & 127];
    size_t base = (size_t)(q >> 2) * NGS * 4 + (q & 3);
    for (int j = 0; j < NSUB / 2; ++j) {
      int s = 2 * j + sh;
      ushort b = cm[base + (size_t)(slice * NSUB + s) * 4];
      if (__uint_as_float((unsigned)b << 16) >= tq) hit[s] = 1;
    }
  }
  __syncthreads();
  // compact hit subs (wave 0)
  if (tid < 64) {
    int total = 0;
    #pragma unroll
    for (int r = 0; r < 2; ++r) {
      int idx = r * 64 + tid;
      bool f = (idx < NSUB) && hit[idx];
      unsigned long long bm = __ballot(f);
      int pos = total + __popcll(bm & ((1ull << tid) - 1ull));
      if (f) slist[pos] = (ushort)idx;
      total += __popcll(bm);
    }
    if (tid == 0) {
      nhit_s = total;
      #pragma unroll
      for (int p = 0; p < 4; ++p) slist[total + p] = 0xFFFF;
    }
  }
  __syncthreads();
  const int nhit = nhit_s;
  if (nhit == 0) return;
  const int nb = (nhit + 3) >> 2;

  bf16x8 afr[2][4];
  #pragma unroll
  for (int jt = 0; jt < 2; ++jt) {
    int qrow = qbase + w * 32 + jt * 16 + m;
    #pragma unroll
    for (int t = 0; t < 4; ++t)
      afr[jt][t] = *reinterpret_cast<const bf16x8*>(qn + (size_t)qrow * 128 + t * 32 + g * 8);
  }
  const float thrq0 = thr_l[w * 32 + m];        // query of jt=0 (lane m)
  const float thrq1 = thr_l[w * 32 + 16 + m];   // query of jt=1

  stage_list(sn, &st[0][0], &slist[0], s0, s1, tid);
  __syncthreads();

  int buf = 0;
  for (int b = 0; b < nb; ++b) {
    if (b + 1 < nb) stage_list(sn, &st[buf ^ 1][0], &slist[(b + 1) * 4], s0, s1, tid);
    const ushort* stc = &st[buf][0];
    #pragma unroll
    for (int ct = 0; ct < 4; ++ct) {
      const int srow = ct * 16 + m;
      f32x4 a0 = {0.f, 0.f, 0.f, 0.f}, a1 = {0.f, 0.f, 0.f, 0.f};
      #pragma unroll
      for (int t = 0; t < 4; ++t) {
        int cj = (4 * t + g) ^ (srow & 7);
        bf16x8 sfr = *reinterpret_cast<const bf16x8*>(&stc[srow * 128 + cj * 8]);
        a0 = __builtin_amdgcn_mfma_f32_16x16x32_bf16(sfr, afr[0][t], a0, 0, 0, 0);
        a1 = __builtin_amdgcn_mfma_f32_16x16x32_bf16(sfr, afr[1][t], a1, 0, 0, 0);
      }
      int sub = slist[b * 4 + ct];
      if (sub != 0xFFFF) {
        int li0 = sub * 16 + g * 4;    // slice-local support of e=0 (D row)
        bool h0[4], h1[4];
        bool any = false;
        #pragma unroll
        for (int e = 0; e < 4; ++e) {
          bool ok = (li0 + e) < slen;
          h0[e] = ok && (a0[e] >= thrq0);
          h1[e] = ok && (a1[e] >= thrq1);
          any = any || h0[e] || h1[e];
        }
        if (__any(any)) {
          #pragma unroll
          for (int e = 0; e < 4; ++e) {
            if (h0[e]) {
              int q = qbase + w * 32 + m;
              unsigned p = atomicAdd(&cnt[q], 1u);
              if (p < (unsigned)QCAP)
                candq[(size_t)q * QCAP + p] =
                    make_float2(a0[e], __int_as_float(s0 + li0 + e));
            }
            if (h1[e]) {
              int q = qbase + w * 32 + 16 + m;
              unsigned p = atomicAdd(&cnt[q], 1u);
              if (p < (unsigned)QCAP)
                candq[(size_t)q * QCAP + p] =
                    make_float2(a1[e], __int_as_float(s0 + li0 + e));
            }
          }
        }
      }
    }
    __syncthreads();
    buf ^= 1;
  }
}

// One wave per query: gather ~27 candidates, exact (f64) refine ALL,
// bitonic top-16 (tie: lower idx) -> weights -> out.
__global__ __launch_bounds__(64) void merge_refine_k(
    const float* __restrict__ query, const float* __restrict__ supports,
    const float* __restrict__ targets, const unsigned* __restrict__ cnt,
    const float2* __restrict__ candq, float* __restrict__ out) {
  const int q = blockIdx.x, lane = threadIdx.x;
  __shared__ float qh_s[128];
  __shared__ float2 list[QCAP];
  __shared__ float2 refd[QCAP];

  int total = min((int)cnt[q], QCAP);
  if (lane < total) list[lane] = candq[(size_t)q * QCAP + lane];

  float2 qv = *reinterpret_cast<const float2*>(query + (size_t)q * 128 + lane * 2);
  double qss = (double)qv.x * qv.x + (double)qv.y * qv.y;
  #pragma unroll
  for (int o = 1; o < 64; o <<= 1) qss += __shfl_xor(qss, o);
  float qn1 = fmaxf((float)sqrt(qss), 1e-12f);
  qh_s[lane * 2] = qv.x / qn1;
  qh_s[lane * 2 + 1] = qv.y / qn1;
  __syncthreads();

  const int g16 = lane >> 4, m16 = lane & 15;
  float qh[8];
  #pragma unroll
  for (int d = 0; d < 8; ++d) qh[d] = qh_s[m16 * 8 + d];
  int rounds = (total + 3) >> 2;
  for (int r = 0; r < rounds; ++r) {
    int cc = r * 4 + g16;
    bool valid = cc < total;
    float2 ce = valid ? list[cc] : make_float2(0.f, __int_as_float(0));
    int sidx = __float_as_int(ce.y);
    float4 sa = *reinterpret_cast<const float4*>(supports + (size_t)sidx * 128 + m16 * 8);
    float4 sb = *reinterpret_cast<const float4*>(supports + (size_t)sidx * 128 + m16 * 8 + 4);
    float sv[8] = {sa.x, sa.y, sa.z, sa.w, sb.x, sb.y, sb.z, sb.w};
    double ss = 0.0, dt = 0.0;
    #pragma unroll
    for (int d = 0; d < 8; ++d) {
      ss += (double)sv[d] * sv[d];
      dt += (double)qh[d] * sv[d];
    }
    #pragma unroll
    for (int o = 1; o < 16; o <<= 1) {
      ss += __shfl_xor(ss, o);
      dt += __shfl_xor(dt, o);
    }
    if (m16 == 0 && valid) {
      float sn1 = fmaxf((float)sqrt(ss), 1e-12f);
      refd[cc] = make_float2((float)(1.0 - dt / (double)sn1), ce.y);
    }
  }
  __syncthreads();

  float dv = (lane < total) ? refd[lane].x : 3.0e38f;
  unsigned di = (lane < total) ? (unsigned)__float_as_int(refd[lane].y) : 0xFFFFFFFFu;
  bitonic64(dv, di, lane);  // ascending (d, idx): lanes 0..15 = top-16

  float wv = (lane < 16) ? 1.0f / (dv + 1e-8f) : 0.0f;
  float wsum = wv;
  #pragma unroll
  for (int o = 1; o < 64; o <<= 1) wsum += __shfl_xor(wsum, o);
  float acc[8];
  #pragma unroll
  for (int t = 0; t < 8; ++t) acc[t] = 0.f;
  if (lane < 16) {
    float wn = wv / wsum;
    const float* tp = targets + (size_t)di * 8;
    #pragma unroll
    for (int t = 0; t < 8; ++t) acc[t] = wn * tp[t];
  }
  #pragma unroll
  for (int o = 1; o < 16; o <<= 1) {
    #pragma unroll
    for (int t = 0; t < 8; ++t) acc[t] += __shfl_xor(acc[t], o);
  }
  if (lane == 0) {
    #pragma unroll
    for (int t = 0; t < 8; ++t) out[(size_t)q * 8 + t] = acc[t];
  }
}

extern "C" void kernel_launch(void* const* d_in, const int* in_sizes, int n_in,
                              void* d_out, int out_size, void* d_ws, size_t ws_size,
                              hipStream_t stream) {
  const float* query = (const float*)d_in[0];
  const float* supports = (const float*)d_in[1];
  const float* targets = (const float*)d_in[2];
  float* out = (float*)d_out;
  const int D = 128;
  const int B = in_sizes[0] / D;   // 2048
  const int N = in_sizes[1] / D;   // 100000

  char* ws = (char*)d_ws;
  size_t off = 0;
  ushort* sn = (ushort*)(ws + off); off += (size_t)N * D * 2;
  off = (off + 255) & ~(size_t)255;
  ushort* qn = (ushort*)(ws + off); off += (size_t)B * D * 2;
  off = (off + 255) & ~(size_t)255;
  ushort* cm = (ushort*)(ws + off); off += (size_t)B * NGS * 2;        // 26.2MB
  off = (off + 255) & ~(size_t)255;
  float* thr = (float*)(ws + off); off += (size_t)B * 4;
  off = (off + 255) & ~(size_t)255;
  unsigned* cnt = (unsigned*)(ws + off); off += (size_t)B * 4;
  off = (off + 255) & ~(size_t)255;
  float2* candq = (float2*)(ws + off); off += (size_t)B * QCAP * sizeof(float2);
  if (off > ws_size) return;

  hipMemsetAsync(cnt, 0, (size_t)B * 4, stream);
  hipLaunchKernelGGL(norm_rows_k, dim3((N + 3) / 4), dim3(256), 0, stream, supports, sn, N);
  hipLaunchKernelGGL(norm_rows_k, dim3((B + 3) / 4), dim3(256), 0, stream, query, qn, B);
  int nblk = (B / BQ) * NSLICES;  // 1280
  hipLaunchKernelGGL(pass1_k, dim3(nblk), dim3(256), 0, stream, qn, sn, cm, N);
  hipLaunchKernelGGL(thr_k, dim3(B), dim3(64), 0, stream, cm, thr);
  hipLaunchKernelGGL(pass2_k, dim3(nblk), dim3(256), 0, stream, qn, sn, cm, thr, cnt, candq, N);
  hipLaunchKernelGGL(merge_refine_k, dim3(B), dim3(64), 0, stream, query, supports, targets, cnt, candq, out);
}

// Round 11
// 219.218 us; speedup vs baseline: 1.0754x; 1.0754x over previous
//
#include <hip/hip_runtime.h>

// SHGR kNN head: cosine distance, top-16, inverse-distance weighted target average.
// B=2048, N=100000, D=128, T=8, k=16.
//
// Pipeline:
//   1. norm_rows_k: L2-normalize supports & queries -> bf16 (ushort bits) in ws.
//   2. pass1_k: bf16 MFMA (TRANSPOSED: D[support][query]); 2-wave blocks with
//      64 queries/wave -> block LDS reads halved vs 4-wave/32q (LDS pipe was
//      the binding resource); per-(query,16-support sub) max -> cm (global,
//      bf16 down-rounded, packed [q/4][gs][q%4]) via 16-lane store_short.
//   3. thr_k: thr[q] = (16th-largest of 6400 sub-maxes) - 0.013 margin.
//      [16th submax <= true 16th score; margin covers bf16 score error
//      (<=2.5e-3 worst case) with 5x slack; E[cands] = 16*exp(41*margin) ~ 27]
//   4. pass2_k: per (qtile,slice) block: find hit subs (stored max >= thr),
//      batch 4 subs -> staged 64-row tile, recompute scores (transposed MFMA),
//      emit scores >= thr to a per-query global list (cap 64).
//   5. merge_refine_k: per query, exact (f64) refine ALL ~27 candidates,
//      bitonic top-16 -> weights -> gather targets -> out.
//
// NOTE (R7): update_dpp row_ror gave wrong submaxes on gfx950 -> shfl_xor only.
// NOTE (R10): grid 1280 @ 32KB LDS -> 4+1 scheduling rounds (160KiB exact-fit
// failed); reverted to grid 1024 = exact 4 blocks/CU.

#define NSLICES 64
#define CN 64
#define BQ 128
#define NSUB 100                 // subs per slice = 25 chunks * 4
#define NGS (NSLICES * NSUB)     // 6400 subs per query
#define QCAP 64                  // per-query candidate list; E=27, P(>64)~1e-9
#define THR_MARGIN 0.013f

typedef __bf16 bf16x8 __attribute__((ext_vector_type(8)));
typedef float f32x4 __attribute__((ext_vector_type(4)));

__device__ __forceinline__ ushort f2bf_rne(float f) {
  unsigned u = __float_as_uint(f);
  return (ushort)((u + 0x7FFFu + ((u >> 16) & 1u)) >> 16);
}
// round toward -inf in bf16 (stored max <= true max)
__device__ __forceinline__ ushort f2bf_down(float f) {
  unsigned u = __float_as_uint(f);
  return (ushort)((u >> 16) + (u >> 31));
}
__device__ __forceinline__ unsigned bf2key(ushort b) {
  return (unsigned)(b ^ ((b & 0x8000u) ? 0xFFFFu : 0x8000u));
}

// Full-wave bitonic sort, ascending in (v, i) lexicographic.
__device__ __forceinline__ void bitonic64(float& v, unsigned& i, int lane) {
  #pragma unroll
  for (int k = 2; k <= 64; k <<= 1) {
    #pragma unroll
    for (int j = k >> 1; j > 0; j >>= 1) {
      float pv = __shfl_xor(v, j);
      unsigned pi = (unsigned)__shfl_xor((int)i, j);
      bool up = ((lane & k) == 0);
      bool lower = ((lane & j) == 0);
      bool gt = (v > pv) || (v == pv && i > pi);
      bool keep = (up == lower) ? !gt : gt;
      if (!keep) { v = pv; i = pi; }
    }
  }
}

__global__ __launch_bounds__(256) void norm_rows_k(const float* __restrict__ x,
                                                   ushort* __restrict__ xb,
                                                   int nrows) {
  int row = blockIdx.x * 4 + (threadIdx.x >> 6);
  int lane = threadIdx.x & 63;
  if (row >= nrows) return;
  float2 v = *reinterpret_cast<const float2*>(x + (size_t)row * 128 + lane * 2);
  float ss = v.x * v.x + v.y * v.y;
  #pragma unroll
  for (int o = 1; o < 64; o <<= 1) ss += __shfl_xor(ss, o);
  float inv = 1.0f / fmaxf(sqrtf(ss), 1e-12f);
  ushort2 h = make_ushort2(f2bf_rne(v.x * inv), f2bf_rne(v.y * inv));
  *reinterpret_cast<ushort2*>(xb + (size_t)row * 128 + lane * 2) = h;
}

// Stage 64x128 bf16 chunk with 128 threads: linear LDS dest + inverse-swizzled
// global source (8 x 16B per thread).
__device__ __forceinline__ void stage128(const ushort* __restrict__ sn,
                                         ushort* dst, int cb, int s1, int tid) {
  #pragma unroll
  for (int r = 0; r < 8; ++r) {
    int o = (r << 11) + tid * 16;
    int row = o >> 8;
    int dj = (o >> 4) & 15;
    int sj = dj ^ (row & 7);
    int srow = min(cb + row, s1 - 1);
    __builtin_amdgcn_global_load_lds(
        (const unsigned int*)(sn + (size_t)srow * 128 + sj * 8),
        (unsigned int*)(dst + (o >> 1)), 16, 0, 0);
  }
}

// Stage 64x128 bf16 chunk with 256 threads (pass2).
__device__ __forceinline__ void stage_lin(const ushort* __restrict__ sn,
                                          ushort* dst, int cb, int s1, int tid) {
  #pragma unroll
  for (int r = 0; r < 4; ++r) {
    int o = (r << 12) + tid * 16;
    int row = o >> 8;
    int dj = (o >> 4) & 15;
    int sj = dj ^ (row & 7);
    int srow = min(cb + row, s1 - 1);
    __builtin_amdgcn_global_load_lds(
        (const unsigned int*)(sn + (size_t)srow * 128 + sj * 8),
        (unsigned int*)(dst + (o >> 1)), 16, 0, 0);
  }
}

// Stage a gathered batch of 4 sub-chunks (16 rows each) from slist (pass2).
__device__ __forceinline__ void stage_list(const ushort* __restrict__ sn,
                                           ushort* dst, const ushort* slist_b,
                                           int s0, int s1, int tid) {
  #pragma unroll
  for (int r = 0; r < 4; ++r) {
    int o = (r << 12) + tid * 16;
    int row = o >> 8;
    int dj = (o >> 4) & 15;
    int sj = dj ^ (row & 7);
    int sub = slist_b[row >> 4];
    int lrow = (sub == 0xFFFF) ? 0 : sub * 16 + (row & 15);
    int srow = min(s0 + lrow, s1 - 1);
    __builtin_amdgcn_global_load_lds(
        (const unsigned int*)(sn + (size_t)srow * 128 + sj * 8),
        (unsigned int*)(dst + (o >> 1)), 16, 0, 0);
  }
}

// Pass 1: sub-chunk maxes. 1024 blocks (128 thr = 2 waves, 64 queries/wave),
// XCD-decoded (8 slices/XCD). Transposed MFMA: lane holds 4 supports x 1 query.
__global__ __launch_bounds__(128, 2) void pass1_k(
    const ushort* __restrict__ qn, const ushort* __restrict__ sn,
    ushort* __restrict__ cm, int N) {
  __shared__ ushort st[2][CN * 128];
  const int tid = threadIdx.x;
  const int w = tid >> 6, lane = tid & 63, g = lane >> 4, m = lane & 15;
  const int L = blockIdx.x;             // 1024 = 8 xcd * (16 qtile * 8 slice)
  const int xcd = L & 7, i6 = L >> 3;
  const int qtile = i6 & 15;
  const int slice = (xcd << 3) | (i6 >> 4);
  const int qbase = qtile * BQ;
  const int SLICE = (N + NSLICES - 1) / NSLICES;  // 1563
  const int s0 = slice * SLICE;
  const int s1 = min(N, s0 + SLICE);
  const int nch = (s1 - s0 + CN - 1) / CN;  // 25 (24 for last slice)

  stage128(sn, &st[0][0], s0, s1, tid);

  // Query fragments (B operand), 64 queries/wave: k = 32*t + 8*g + e, col = m.
  bf16x8 afr[4][4];
  #pragma unroll
  for (int jt = 0; jt < 4; ++jt) {
    int qrow = qbase + w * 64 + jt * 16 + m;
    #pragma unroll
    for (int t = 0; t < 4; ++t)
      afr[jt][t] = *reinterpret_cast<const bf16x8*>(qn + (size_t)qrow * 128 + t * 32 + g * 8);
  }
  __syncthreads();

  int buf = 0;
  for (int ch = 0; ch < nch; ++ch) {
    const int cb = s0 + ch * CN;
    if (ch + 1 < nch) stage128(sn, &st[buf ^ 1][0], cb + CN, s1, tid);
    const ushort* stc = &st[buf][0];
    const bool lastch = (ch == nch - 1);
    #pragma unroll
    for (int ct = 0; ct < 4; ++ct) {
      const int srow = ct * 16 + m;     // A-operand row = support (lane m)
      bf16x8 sfr[4];
      #pragma unroll
      for (int t = 0; t < 4; ++t) {
        int cj = (4 * t + g) ^ (srow & 7);
        sfr[t] = *reinterpret_cast<const bf16x8*>(&stc[srow * 128 + cj * 8]);
      }
      const int gs = slice * NSUB + ch * 4 + ct;
      const int si = cb + ct * 16 + g * 4;   // support of e=0 (D row base)
      #pragma unroll
      for (int jt = 0; jt < 4; ++jt) {
        f32x4 a = {0.f, 0.f, 0.f, 0.f};
        #pragma unroll
        for (int t = 0; t < 4; ++t)
          a = __builtin_amdgcn_mfma_f32_16x16x32_bf16(sfr[t], afr[jt][t], a, 0, 0, 0);
        // mask invalid supports (clamped duplicate rows) -- last chunk only
        if (lastch) {
          #pragma unroll
          for (int e = 0; e < 4; ++e)
            if (si + e >= s1) a[e] = -3.0e38f;
        }
        // max over 4 supports (in-reg) then over the 4 g-groups (2 shfl)
        float v = fmaxf(fmaxf(a[0], a[1]), fmaxf(a[2], a[3]));
        v = fmaxf(v, __shfl_xor(v, 16));
        v = fmaxf(v, __shfl_xor(v, 32));
        if (g == 0) {  // 16 lanes store 2B each (one store instruction)
          int q = qbase + w * 64 + jt * 16 + m;
          cm[((size_t)(q >> 2) * NGS + gs) * 4 + (q & 3)] = f2bf_down(v);
        }
      }
    }
    __syncthreads();
    buf ^= 1;
  }

  // fill unwritten tail subs (nch < 25 on the last slice) with bf16 -inf
  const int miss = NSUB - nch * 4;
  for (int idx = tid; idx < miss * BQ; idx += 128) {
    int sub = nch * 4 + idx / BQ;
    int q = qbase + (idx % BQ);
    cm[((size_t)(q >> 2) * NGS + (size_t)(slice * NSUB + sub)) * 4 + (q & 3)] = 0xFF80;
  }
}

// thr[q] = 16th-largest of the 6400 sub-maxes, minus margin. One wave per query.
__global__ __launch_bounds__(64) void thr_k(const ushort* __restrict__ cm,
                                            float* __restrict__ thr) {
  const int q = blockIdx.x, lane = threadIdx.x;
  const size_t base = (size_t)(q >> 2) * NGS * 4 + (q & 3);
  unsigned keys[NGS / 128];
  #pragma unroll
  for (int j = 0; j < NGS / 128; ++j) {
    unsigned k0 = bf2key(cm[base + (size_t)(lane + 128 * j) * 4]);
    unsigned k1 = bf2key(cm[base + (size_t)(lane + 64 + 128 * j) * 4]);
    keys[j] = k0 | (k1 << 16);
  }
  unsigned res = 0;
  for (int b = 15; b >= 0; --b) {
    unsigned t = res | (1u << b);
    int c = 0;
    #pragma unroll
    for (int j = 0; j < NGS / 128; ++j)
      c += (int)((keys[j] & 0xFFFFu) >= t) + (int)((keys[j] >> 16) >= t);
    #pragma unroll
    for (int o = 1; o < 64; o <<= 1) c += __shfl_xor(c, o);
    if (c >= 16) res = t;
  }
  if (lane == 0) {
    ushort b16 = (ushort)((res & 0x8000u) ? (res ^ 0x8000u) : (res ^ 0xFFFFu));
    thr[q] = __uint_as_float((unsigned)b16 << 16) - THR_MARGIN;
  }
}

// Pass 2: visit only hit subs (stored max >= thr), 4 per staged batch.
// Transposed MFMA: lane holds 4 supports x 1 query; thr per lane hoisted.
__global__ __launch_bounds__(256, 4) void pass2_k(
    const ushort* __restrict__ qn, const ushort* __restrict__ sn,
    const ushort* __restrict__ cm, const float* __restrict__ thr,
    unsigned* __restrict__ cnt, float2* __restrict__ candq, int N) {
  __shared__ ushort st[2][CN * 128];
  __shared__ float thr_l[BQ];
  __shared__ unsigned char hit[NSUB];
  __shared__ ushort slist[NSUB + 4];
  __shared__ int nhit_s;

  const int tid = threadIdx.x;
  const int w = tid >> 6, lane = tid & 63, g = lane >> 4, m = lane & 15;
  const int L = blockIdx.x;
  const int xcd = L & 7, i6 = L >> 3;
  const int qtile = i6 & 15;
  const int slice = (xcd << 3) | (i6 >> 4);
  const int qbase = qtile * BQ;
  const int SLICE = (N + NSLICES - 1) / NSLICES;
  const int s0 = slice * SLICE;
  const int s1 = min(N, s0 + SLICE);
  const int slen = s1 - s0;

  if (tid < BQ) thr_l[tid] = thr[qbase + tid];
  if (tid < NSUB) hit[tid] = 0;
  __syncthreads();

  // hit scan: thread (q = tid&127, parity = tid>>7) covers s = 2j+parity
  {
    int q = qbase + (tid & 127);
    int sh = tid >> 7;
    float tq = thr_l[tid & 127];
    size_t base = (size_t)(q >> 2) * NGS * 4 + (q & 3);
    for (int j = 0; j < NSUB / 2; ++j) {
      int s = 2 * j + sh;
      ushort b = cm[base + (size_t)(slice * NSUB + s) * 4];
      if (__uint_as_float((unsigned)b << 16) >= tq) hit[s] = 1;
    }
  }
  __syncthreads();
  // compact hit subs (wave 0)
  if (tid < 64) {
    int total = 0;
    #pragma unroll
    for (int r = 0; r < 2; ++r) {
      int idx = r * 64 + tid;
      bool f = (idx < NSUB) && hit[idx];
      unsigned long long bm = __ballot(f);
      int pos = total + __popcll(bm & ((1ull << tid) - 1ull));
      if (f) slist[pos] = (ushort)idx;
      total += __popcll(bm);
    }
    if (tid == 0) {
      nhit_s = total;
      #pragma unroll
      for (int p = 0; p < 4; ++p) slist[total + p] = 0xFFFF;
    }
  }
  __syncthreads();
  const int nhit = nhit_s;
  if (nhit == 0) return;
  const int nb = (nhit + 3) >> 2;

  bf16x8 afr[2][4];
  #pragma unroll
  for (int jt = 0; jt < 2; ++jt) {
    int qrow = qbase + w * 32 + jt * 16 + m;
    #pragma unroll
    for (int t = 0; t < 4; ++t)
      afr[jt][t] = *reinterpret_cast<const bf16x8*>(qn + (size_t)qrow * 128 + t * 32 + g * 8);
  }
  const float thrq0 = thr_l[w * 32 + m];        // query of jt=0 (lane m)
  const float thrq1 = thr_l[w * 32 + 16 + m];   // query of jt=1

  stage_list(sn, &st[0][0], &slist[0], s0, s1, tid);
  __syncthreads();

  int buf = 0;
  for (int b = 0; b < nb; ++b) {
    if (b + 1 < nb) stage_list(sn, &st[buf ^ 1][0], &slist[(b + 1) * 4], s0, s1, tid);
    const ushort* stc = &st[buf][0];
    #pragma unroll
    for (int ct = 0; ct < 4; ++ct) {
      const int srow = ct * 16 + m;
      f32x4 a0 = {0.f, 0.f, 0.f, 0.f}, a1 = {0.f, 0.f, 0.f, 0.f};
      #pragma unroll
      for (int t = 0; t < 4; ++t) {
        int cj = (4 * t + g) ^ (srow & 7);
        bf16x8 sfr = *reinterpret_cast<const bf16x8*>(&stc[srow * 128 + cj * 8]);
        a0 = __builtin_amdgcn_mfma_f32_16x16x32_bf16(sfr, afr[0][t], a0, 0, 0, 0);
        a1 = __builtin_amdgcn_mfma_f32_16x16x32_bf16(sfr, afr[1][t], a1, 0, 0, 0);
      }
      int sub = slist[b * 4 + ct];
      if (sub != 0xFFFF) {
        int li0 = sub * 16 + g * 4;    // slice-local support of e=0 (D row)
        bool h0[4], h1[4];
        bool any = false;
        #pragma unroll
        for (int e = 0; e < 4; ++e) {
          bool ok = (li0 + e) < slen;
          h0[e] = ok && (a0[e] >= thrq0);
          h1[e] = ok && (a1[e] >= thrq1);
          any = any || h0[e] || h1[e];
        }
        if (__any(any)) {
          #pragma unroll
          for (int e = 0; e < 4; ++e) {
            if (h0[e]) {
              int q = qbase + w * 32 + m;
              unsigned p = atomicAdd(&cnt[q], 1u);
              if (p < (unsigned)QCAP)
                candq[(size_t)q * QCAP + p] =
                    make_float2(a0[e], __int_as_float(s0 + li0 + e));
            }
            if (h1[e]) {
              int q = qbase + w * 32 + 16 + m;
              unsigned p = atomicAdd(&cnt[q], 1u);
              if (p < (unsigned)QCAP)
                candq[(size_t)q * QCAP + p] =
                    make_float2(a1[e], __int_as_float(s0 + li0 + e));
            }
          }
        }
      }
    }
    __syncthreads();
    buf ^= 1;
  }
}

// One wave per query: gather ~27 candidates, exact (f64) refine ALL,
// bitonic top-16 (tie: lower idx) -> weights -> out.
__global__ __launch_bounds__(64) void merge_refine_k(
    const float* __restrict__ query, const float* __restrict__ supports,
    const float* __restrict__ targets, const unsigned* __restrict__ cnt,
    const float2* __restrict__ candq, float* __restrict__ out) {
  const int q = blockIdx.x, lane = threadIdx.x;
  __shared__ float qh_s[128];
  __shared__ float2 list[QCAP];
  __shared__ float2 refd[QCAP];

  int total = min((int)cnt[q], QCAP);
  if (lane < total) list[lane] = candq[(size_t)q * QCAP + lane];

  float2 qv = *reinterpret_cast<const float2*>(query + (size_t)q * 128 + lane * 2);
  double qss = (double)qv.x * qv.x + (double)qv.y * qv.y;
  #pragma unroll
  for (int o = 1; o < 64; o <<= 1) qss += __shfl_xor(qss, o);
  float qn1 = fmaxf((float)sqrt(qss), 1e-12f);
  qh_s[lane * 2] = qv.x / qn1;
  qh_s[lane * 2 + 1] = qv.y / qn1;
  __syncthreads();

  const int g16 = lane >> 4, m16 = lane & 15;
  float qh[8];
  #pragma unroll
  for (int d = 0; d < 8; ++d) qh[d] = qh_s[m16 * 8 + d];
  int rounds = (total + 3) >> 2;
  for (int r = 0; r < rounds; ++r) {
    int cc = r * 4 + g16;
    bool valid = cc < total;
    float2 ce = valid ? list[cc] : make_float2(0.f, __int_as_float(0));
    int sidx = __float_as_int(ce.y);
    float4 sa = *reinterpret_cast<const float4*>(supports + (size_t)sidx * 128 + m16 * 8);
    float4 sb = *reinterpret_cast<const float4*>(supports + (size_t)sidx * 128 + m16 * 8 + 4);
    float sv[8] = {sa.x, sa.y, sa.z, sa.w, sb.x, sb.y, sb.z, sb.w};
    double ss = 0.0, dt = 0.0;
    #pragma unroll
    for (int d = 0; d < 8; ++d) {
      ss += (double)sv[d] * sv[d];
      dt += (double)qh[d] * sv[d];
    }
    #pragma unroll
    for (int o = 1; o < 16; o <<= 1) {
      ss += __shfl_xor(ss, o);
      dt += __shfl_xor(dt, o);
    }
    if (m16 == 0 && valid) {
      float sn1 = fmaxf((float)sqrt(ss), 1e-12f);
      refd[cc] = make_float2((float)(1.0 - dt / (double)sn1), ce.y);
    }
  }
  __syncthreads();

  float dv = (lane < total) ? refd[lane].x : 3.0e38f;
  unsigned di = (lane < total) ? (unsigned)__float_as_int(refd[lane].y) : 0xFFFFFFFFu;
  bitonic64(dv, di, lane);  // ascending (d, idx): lanes 0..15 = top-16

  float wv = (lane < 16) ? 1.0f / (dv + 1e-8f) : 0.0f;
  float wsum = wv;
  #pragma unroll
  for (int o = 1; o < 64; o <<= 1) wsum += __shfl_xor(wsum, o);
  float acc[8];
  #pragma unroll
  for (int t = 0; t < 8; ++t) acc[t] = 0.f;
  if (lane < 16) {
    float wn = wv / wsum;
    const float* tp = targets + (size_t)di * 8;
    #pragma unroll
    for (int t = 0; t < 8; ++t) acc[t] = wn * tp[t];
  }
  #pragma unroll
  for (int o = 1; o < 16; o <<= 1) {
    #pragma unroll
    for (int t = 0; t < 8; ++t) acc[t] += __shfl_xor(acc[t], o);
  }
  if (lane == 0) {
    #pragma unroll
    for (int t = 0; t < 8; ++t) out[(size_t)q * 8 + t] = acc[t];
  }
}

extern "C" void kernel_launch(void* const* d_in, const int* in_sizes, int n_in,
                              void* d_out, int out_size, void* d_ws, size_t ws_size,
                              hipStream_t stream) {
  const float* query = (const float*)d_in[0];
  const float* supports = (const float*)d_in[1];
  const float* targets = (const float*)d_in[2];
  float* out = (float*)d_out;
  const int D = 128;
  const int B = in_sizes[0] / D;   // 2048
  const int N = in_sizes[1] / D;   // 100000

  char* ws = (char*)d_ws;
  size_t off = 0;
  ushort* sn = (ushort*)(ws + off); off += (size_t)N * D * 2;
  off = (off + 255) & ~(size_t)255;
  ushort* qn = (ushort*)(ws + off); off += (size_t)B * D * 2;
  off = (off + 255) & ~(size_t)255;
  ushort* cm = (ushort*)(ws + off); off += (size_t)B * NGS * 2;        // 26.2MB
  off = (off + 255) & ~(size_t)255;
  float* thr = (float*)(ws + off); off += (size_t)B * 4;
  off = (off + 255) & ~(size_t)255;
  unsigned* cnt = (unsigned*)(ws + off); off += (size_t)B * 4;
  off = (off + 255) & ~(size_t)255;
  float2* candq = (float2*)(ws + off); off += (size_t)B * QCAP * sizeof(float2);
  if (off > ws_size) return;

  hipMemsetAsync(cnt, 0, (size_t)B * 4, stream);
  hipLaunchKernelGGL(norm_rows_k, dim3((N + 3) / 4), dim3(256), 0, stream, supports, sn, N);
  hipLaunchKernelGGL(norm_rows_k, dim3((B + 3) / 4), dim3(256), 0, stream, query, qn, B);
  int nblk = (B / BQ) * NSLICES;  // 1024
  hipLaunchKernelGGL(pass1_k, dim3(nblk), dim3(128), 0, stream, qn, sn, cm, N);
  hipLaunchKernelGGL(thr_k, dim3(B), dim3(64), 0, stream, cm, thr);
  hipLaunchKernelGGL(pass2_k, dim3(nblk), dim3(256), 0, stream, qn, sn, cm, thr, cnt, candq, N);
  hipLaunchKernelGGL(merge_refine_k, dim3(B), dim3(64), 0, stream, query, supports, targets, cnt, candq, out);
}

// Round 12
// 188.164 us; speedup vs baseline: 1.2529x; 1.1650x over previous
//
#include <hip/hip_runtime.h>

// SHGR kNN head: cosine distance, top-16, inverse-distance weighted target average.
// B=2048, N=100000, D=128, T=8, k=16.
//
// Pipeline (5 dispatches):
//   1. norm_rows_k (fused): L2-normalize supports AND queries -> bf16 in ws.
//   2. pass1_k [R9-proven]: transposed bf16 MFMA (D[support][query]); per-
//      (query,16-support sub) max -> cm (bf16 down-rounded, [q/4][gs][q%4]).
//   3. thr_k: thr[q] = (16th-largest of 6400 sub-maxes) - 0.013 margin; also
//      zeroes cnt[q] (replaces the memset dispatch). 4 queries/block.
//   4. pass2_k [R9-proven]: visit hit subs only (stored max >= thr), batch 4 ->
//      staged tile, recompute scores (bitwise-identical MFMA), emit >= thr to
//      per-query global list (cap 64).
//   5. merge_refine_k: 4 queries/block; exact (f64) refine ALL ~27 cands,
//      bitonic top-16 -> weights -> gather targets -> out.  f64 kept: a rank-
//      16/17 near-tie swap vs numpy costs ~0.06 >> 0.0153 threshold.
//
// NOTE (R7): update_dpp row_ror gave wrong submaxes on gfx950 -> shfl_xor only.
// NOTE (R10/R11): pass1 is wave-count-bound, NOT LDS-pipe-bound. 256thr/4-wave
// blocks, grid 1024 = 4 blk/CU (R9) beats 5-blk exact-fit and 2-wave variants.

#define NSLICES 64
#define CN 64
#define BQ 128
#define NSUB 100                 // subs per slice = 25 chunks * 4
#define NGS (NSLICES * NSUB)     // 6400 subs per query
#define QCAP 64                  // per-query candidate list; E=27, P(>64)~1e-9
#define THR_MARGIN 0.013f

typedef __bf16 bf16x8 __attribute__((ext_vector_type(8)));
typedef float f32x4 __attribute__((ext_vector_type(4)));

__device__ __forceinline__ ushort f2bf_rne(float f) {
  unsigned u = __float_as_uint(f);
  return (ushort)((u + 0x7FFFu + ((u >> 16) & 1u)) >> 16);
}
// round toward -inf in bf16 (stored max <= true max)
__device__ __forceinline__ ushort f2bf_down(float f) {
  unsigned u = __float_as_uint(f);
  return (ushort)((u >> 16) + (u >> 31));
}
__device__ __forceinline__ unsigned bf2key(ushort b) {
  return (unsigned)(b ^ ((b & 0x8000u) ? 0xFFFFu : 0x8000u));
}

// Full-wave bitonic sort, ascending in (v, i) lexicographic.
__device__ __forceinline__ void bitonic64(float& v, unsigned& i, int lane) {
  #pragma unroll
  for (int k = 2; k <= 64; k <<= 1) {
    #pragma unroll
    for (int j = k >> 1; j > 0; j >>= 1) {
      float pv = __shfl_xor(v, j);
      unsigned pi = (unsigned)__shfl_xor((int)i, j);
      bool up = ((lane & k) == 0);
      bool lower = ((lane & j) == 0);
      bool gt = (v > pv) || (v == pv && i > pi);
      bool keep = (up == lower) ? !gt : gt;
      if (!keep) { v = pv; i = pi; }
    }
  }
}

// Fused: rows [0,N) = supports -> sb; rows [N, N+nq) = queries -> qb.
__global__ __launch_bounds__(256) void norm_rows_k(
    const float* __restrict__ sup, const float* __restrict__ qry,
    ushort* __restrict__ sb, ushort* __restrict__ qb, int N, int nq) {
  int row = blockIdx.x * 4 + (threadIdx.x >> 6);
  int lane = threadIdx.x & 63;
  if (row >= N + nq) return;
  const float* src = (row < N) ? (sup + (size_t)row * 128)
                               : (qry + (size_t)(row - N) * 128);
  ushort* dst = (row < N) ? (sb + (size_t)row * 128)
                          : (qb + (size_t)(row - N) * 128);
  float2 v = *reinterpret_cast<const float2*>(src + lane * 2);
  float ss = v.x * v.x + v.y * v.y;
  #pragma unroll
  for (int o = 1; o < 64; o <<= 1) ss += __shfl_xor(ss, o);
  float inv = 1.0f / fmaxf(sqrtf(ss), 1e-12f);
  ushort2 h = make_ushort2(f2bf_rne(v.x * inv), f2bf_rne(v.y * inv));
  *reinterpret_cast<ushort2*>(dst + lane * 2) = h;
}

// Stage 64x128 bf16 chunk: linear LDS dest + inverse-swizzled global source.
__device__ __forceinline__ void stage_lin(const ushort* __restrict__ sn,
                                          ushort* dst, int cb, int s1, int tid) {
  #pragma unroll
  for (int r = 0; r < 4; ++r) {
    int o = (r << 12) + tid * 16;
    int row = o >> 8;
    int dj = (o >> 4) & 15;
    int sj = dj ^ (row & 7);
    int srow = min(cb + row, s1 - 1);
    __builtin_amdgcn_global_load_lds(
        (const unsigned int*)(sn + (size_t)srow * 128 + sj * 8),
        (unsigned int*)(dst + (o >> 1)), 16, 0, 0);
  }
}

// Stage a gathered batch of 4 sub-chunks (16 rows each) from slist.
__device__ __forceinline__ void stage_list(const ushort* __restrict__ sn,
                                           ushort* dst, const ushort* slist_b,
                                           int s0, int s1, int tid) {
  #pragma unroll
  for (int r = 0; r < 4; ++r) {
    int o = (r << 12) + tid * 16;
    int row = o >> 8;
    int dj = (o >> 4) & 15;
    int sj = dj ^ (row & 7);
    int sub = slist_b[row >> 4];
    int lrow = (sub == 0xFFFF) ? 0 : sub * 16 + (row & 15);
    int srow = min(s0 + lrow, s1 - 1);
    __builtin_amdgcn_global_load_lds(
        (const unsigned int*)(sn + (size_t)srow * 128 + sj * 8),
        (unsigned int*)(dst + (o >> 1)), 16, 0, 0);
  }
}

// Pass 1 [R9-proven]: sub-chunk maxes. 1024 blocks XCD-decoded (8 slices/XCD).
// Transposed MFMA: D[row=support][col=query]; lane holds 4 supports x 1 query.
__global__ __launch_bounds__(256, 4) void pass1_k(
    const ushort* __restrict__ qn, const ushort* __restrict__ sn,
    ushort* __restrict__ cm, int N) {
  __shared__ ushort st[2][CN * 128];
  const int tid = threadIdx.x;
  const int w = tid >> 6, lane = tid & 63, g = lane >> 4, m = lane & 15;
  const int L = blockIdx.x;             // 1024 = 8 xcd * (16 qtile * 8 slice)
  const int xcd = L & 7, i6 = L >> 3;
  const int qtile = i6 & 15;
  const int slice = (xcd << 3) | (i6 >> 4);
  const int qbase = qtile * BQ;
  const int SLICE = (N + NSLICES - 1) / NSLICES;  // 1563
  const int s0 = slice * SLICE;
  const int s1 = min(N, s0 + SLICE);
  const int nch = (s1 - s0 + CN - 1) / CN;  // 25 (24 for last slice)

  stage_lin(sn, &st[0][0], s0, s1, tid);

  // Query fragments (B operand): k = 32*t + 8*g + e, col = m.
  bf16x8 afr[2][4];
  #pragma unroll
  for (int jt = 0; jt < 2; ++jt) {
    int qrow = qbase + w * 32 + jt * 16 + m;
    #pragma unroll
    for (int t = 0; t < 4; ++t)
      afr[jt][t] = *reinterpret_cast<const bf16x8*>(qn + (size_t)qrow * 128 + t * 32 + g * 8);
  }
  __syncthreads();

  int buf = 0;
  for (int ch = 0; ch < nch; ++ch) {
    const int cb = s0 + ch * CN;
    if (ch + 1 < nch) stage_lin(sn, &st[buf ^ 1][0], cb + CN, s1, tid);
    const ushort* stc = &st[buf][0];
    const bool lastch = (ch == nch - 1);
    #pragma unroll
    for (int ct = 0; ct < 4; ++ct) {
      const int srow = ct * 16 + m;     // A-operand row = support (lane m)
      f32x4 a0 = {0.f, 0.f, 0.f, 0.f}, a1 = {0.f, 0.f, 0.f, 0.f};
      #pragma unroll
      for (int t = 0; t < 4; ++t) {
        int cj = (4 * t + g) ^ (srow & 7);
        bf16x8 sfr = *reinterpret_cast<const bf16x8*>(&stc[srow * 128 + cj * 8]);
        a0 = __builtin_amdgcn_mfma_f32_16x16x32_bf16(sfr, afr[0][t], a0, 0, 0, 0);
        a1 = __builtin_amdgcn_mfma_f32_16x16x32_bf16(sfr, afr[1][t], a1, 0, 0, 0);
      }
      // mask invalid supports (D rows: support = cb + ct*16 + g*4 + e)
      if (lastch) {
        int si = cb + ct * 16 + g * 4;
        #pragma unroll
        for (int e = 0; e < 4; ++e) {
          if (si + e >= s1) { a0[e] = -3.0e38f; a1[e] = -3.0e38f; }
        }
      }
      // in-register max over 4 supports, then across the 4 g-groups
      float v0 = fmaxf(fmaxf(a0[0], a0[1]), fmaxf(a0[2], a0[3]));
      float v1 = fmaxf(fmaxf(a1[0], a1[1]), fmaxf(a1[2], a1[3]));
      v0 = fmaxf(v0, __shfl_xor(v0, 16));
      v0 = fmaxf(v0, __shfl_xor(v0, 32));
      v1 = fmaxf(v1, __shfl_xor(v1, 16));
      v1 = fmaxf(v1, __shfl_xor(v1, 32));
      // pack 4 queries' bf16 submaxes -> 8B store on lanes (g==0, m%4==0)
      unsigned u0 = (unsigned)f2bf_down(v0);
      unsigned u1 = (unsigned)f2bf_down(v1);
      unsigned w0 = u0 | ((unsigned)__shfl_xor((int)u0, 1) << 16);
      unsigned w1 = u1 | ((unsigned)__shfl_xor((int)u1, 1) << 16);
      unsigned x0 = (unsigned)__shfl_xor((int)w0, 2);
      unsigned x1 = (unsigned)__shfl_xor((int)w1, 2);
      if (g == 0 && (m & 3) == 0) {
        int gs = slice * NSUB + ch * 4 + ct;
        int q0 = qbase + w * 32 + m;       // jt=0 queries q0..q0+3 (q0%4==0)
        int q1 = q0 + 16;                  // jt=1
        *reinterpret_cast<uint2*>(cm + ((size_t)(q0 >> 2) * NGS + gs) * 4) =
            make_uint2(w0, x0);
        *reinterpret_cast<uint2*>(cm + ((size_t)(q1 >> 2) * NGS + gs) * 4) =
            make_uint2(w1, x1);
      }
    }
    __syncthreads();
    buf ^= 1;
  }

  // fill unwritten tail subs (nch < 25 on the last slice) with bf16 -inf
  const int miss = NSUB - nch * 4;
  for (int idx = tid; idx < miss * BQ; idx += 256) {
    int sub = nch * 4 + idx / BQ;
    int q = qbase + (idx % BQ);
    cm[((size_t)(q >> 2) * NGS + (size_t)(slice * NSUB + sub)) * 4 + (q & 3)] = 0xFF80;
  }
}

// thr[q] = 16th-largest of the 6400 sub-maxes, minus margin; zero cnt[q].
// 4 queries per 256-thread block (one per wave) -> q-group shares cache lines.
__global__ __launch_bounds__(256) void thr_k(const ushort* __restrict__ cm,
                                             float* __restrict__ thr,
                                             unsigned* __restrict__ cnt) {
  const int q = blockIdx.x * 4 + (threadIdx.x >> 6);
  const int lane = threadIdx.x & 63;
  const size_t base = (size_t)(q >> 2) * NGS * 4 + (q & 3);
  unsigned keys[NGS / 128];
  #pragma unroll
  for (int j = 0; j < NGS / 128; ++j) {
    unsigned k0 = bf2key(cm[base + (size_t)(lane + 128 * j) * 4]);
    unsigned k1 = bf2key(cm[base + (size_t)(lane + 64 + 128 * j) * 4]);
    keys[j] = k0 | (k1 << 16);
  }
  unsigned res = 0;
  for (int b = 15; b >= 0; --b) {
    unsigned t = res | (1u << b);
    int c = 0;
    #pragma unroll
    for (int j = 0; j < NGS / 128; ++j)
      c += (int)((keys[j] & 0xFFFFu) >= t) + (int)((keys[j] >> 16) >= t);
    #pragma unroll
    for (int o = 1; o < 64; o <<= 1) c += __shfl_xor(c, o);
    if (c >= 16) res = t;
  }
  if (lane == 0) {
    ushort b16 = (ushort)((res & 0x8000u) ? (res ^ 0x8000u) : (res ^ 0xFFFFu));
    thr[q] = __uint_as_float((unsigned)b16 << 16) - THR_MARGIN;
    cnt[q] = 0;
  }
}

// Pass 2 [R9-proven]: visit only hit subs (stored max >= thr), 4 per batch.
// Transposed MFMA: lane holds 4 supports x 1 query; thr per lane hoisted.
__global__ __launch_bounds__(256, 4) void pass2_k(
    const ushort* __restrict__ qn, const ushort* __restrict__ sn,
    const ushort* __restrict__ cm, const float* __restrict__ thr,
    unsigned* __restrict__ cnt, float2* __restrict__ candq, int N) {
  __shared__ ushort st[2][CN * 128];
  __shared__ float thr_l[BQ];
  __shared__ unsigned char hit[NSUB];
  __shared__ ushort slist[NSUB + 4];
  __shared__ int nhit_s;

  const int tid = threadIdx.x;
  const int w = tid >> 6, lane = tid & 63, g = lane >> 4, m = lane & 15;
  const int L = blockIdx.x;
  const int xcd = L & 7, i6 = L >> 3;
  const int qtile = i6 & 15;
  const int slice = (xcd << 3) | (i6 >> 4);
  const int qbase = qtile * BQ;
  const int SLICE = (N + NSLICES - 1) / NSLICES;
  const int s0 = slice * SLICE;
  const int s1 = min(N, s0 + SLICE);
  const int slen = s1 - s0;

  if (tid < BQ) thr_l[tid] = thr[qbase + tid];
  if (tid < NSUB) hit[tid] = 0;
  __syncthreads();

  // hit scan: thread (q = tid&127, parity = tid>>7) covers s = 2j+parity
  {
    int q = qbase + (tid & 127);
    int sh = tid >> 7;
    float tq = thr_l[tid & 127];
    size_t base = (size_t)(q >> 2) * NGS * 4 + (q & 3);
    for (int j = 0; j < NSUB / 2; ++j) {
      int s = 2 * j + sh;
      ushort b = cm[base + (size_t)(slice * NSUB + s) * 4];
      if (__uint_as_float((unsigned)b << 16) >= tq) hit[s] = 1;
    }
  }
  __syncthreads();
  // compact hit subs (wave 0)
  if (tid < 64) {
    int total = 0;
    #pragma unroll
    for (int r = 0; r < 2; ++r) {
      int idx = r * 64 + tid;
      bool f = (idx < NSUB) && hit[idx];
      unsigned long long bm = __ballot(f);
      int pos = total + __popcll(bm & ((1ull << tid) - 1ull));
      if (f) slist[pos] = (ushort)idx;
      total += __popcll(bm);
    }
    if (tid == 0) {
      nhit_s = total;
      #pragma unroll
      for (int p = 0; p < 4; ++p) slist[total + p] = 0xFFFF;
    }
  }
  __syncthreads();
  const int nhit = nhit_s;
  if (nhit == 0) return;
  const int nb = (nhit + 3) >> 2;

  bf16x8 afr[2][4];
  #pragma unroll
  for (int jt = 0; jt < 2; ++jt) {
    int qrow = qbase + w * 32 + jt * 16 + m;
    #pragma unroll
    for (int t = 0; t < 4; ++t)
      afr[jt][t] = *reinterpret_cast<const bf16x8*>(qn + (size_t)qrow * 128 + t * 32 + g * 8);
  }
  const float thrq0 = thr_l[w * 32 + m];        // query of jt=0 (lane m)
  const float thrq1 = thr_l[w * 32 + 16 + m];   // query of jt=1

  stage_list(sn, &st[0][0], &slist[0], s0, s1, tid);
  __syncthreads();

  int buf = 0;
  for (int b = 0; b < nb; ++b) {
    if (b + 1 < nb) stage_list(sn, &st[buf ^ 1][0], &slist[(b + 1) * 4], s0, s1, tid);
    const ushort* stc = &st[buf][0];
    #pragma unroll
    for (int ct = 0; ct < 4; ++ct) {
      const int srow = ct * 16 + m;
      f32x4 a0 = {0.f, 0.f, 0.f, 0.f}, a1 = {0.f, 0.f, 0.f, 0.f};
      #pragma unroll
      for (int t = 0; t < 4; ++t) {
        int cj = (4 * t + g) ^ (srow & 7);
        bf16x8 sfr = *reinterpret_cast<const bf16x8*>(&stc[srow * 128 + cj * 8]);
        a0 = __builtin_amdgcn_mfma_f32_16x16x32_bf16(sfr, afr[0][t], a0, 0, 0, 0);
        a1 = __builtin_amdgcn_mfma_f32_16x16x32_bf16(sfr, afr[1][t], a1, 0, 0, 0);
      }
      int sub = slist[b * 4 + ct];
      if (sub != 0xFFFF) {
        int li0 = sub * 16 + g * 4;    // slice-local support of e=0 (D row)
        bool h0[4], h1[4];
        bool any = false;
        #pragma unroll
        for (int e = 0; e < 4; ++e) {
          bool ok = (li0 + e) < slen;
          h0[e] = ok && (a0[e] >= thrq0);
          h1[e] = ok && (a1[e] >= thrq1);
          any = any || h0[e] || h1[e];
        }
        if (__any(any)) {
          #pragma unroll
          for (int e = 0; e < 4; ++e) {
            if (h0[e]) {
              int q = qbase + w * 32 + m;
              unsigned p = atomicAdd(&cnt[q], 1u);
              if (p < (unsigned)QCAP)
                candq[(size_t)q * QCAP + p] =
                    make_float2(a0[e], __int_as_float(s0 + li0 + e));
            }
            if (h1[e]) {
              int q = qbase + w * 32 + 16 + m;
              unsigned p = atomicAdd(&cnt[q], 1u);
              if (p < (unsigned)QCAP)
                candq[(size_t)q * QCAP + p] =
                    make_float2(a1[e], __int_as_float(s0 + li0 + e));
            }
          }
        }
      }
    }
    __syncthreads();
    buf ^= 1;
  }
}

// 4 queries per 256-thread block (one wave each): gather ~27 candidates,
// exact (f64) refine ALL, bitonic top-16 (tie: lower idx) -> weights -> out.
__global__ __launch_bounds__(256) void merge_refine_k(
    const float* __restrict__ query, const float* __restrict__ supports,
    const float* __restrict__ targets, const unsigned* __restrict__ cnt,
    const float2* __restrict__ candq, float* __restrict__ out) {
  const int W = threadIdx.x >> 6;
  const int q = blockIdx.x * 4 + W;
  const int lane = threadIdx.x & 63;
  __shared__ float qh_s[4][128];
  __shared__ float2 list[4][QCAP];
  __shared__ float2 refd[4][QCAP];

  int total = min((int)cnt[q], QCAP);
  if (lane < total) list[W][lane] = candq[(size_t)q * QCAP + lane];

  float2 qv = *reinterpret_cast<const float2*>(query + (size_t)q * 128 + lane * 2);
  double qss = (double)qv.x * qv.x + (double)qv.y * qv.y;
  #pragma unroll
  for (int o = 1; o < 64; o <<= 1) qss += __shfl_xor(qss, o);
  float qn1 = fmaxf((float)sqrt(qss), 1e-12f);
  qh_s[W][lane * 2] = qv.x / qn1;
  qh_s[W][lane * 2 + 1] = qv.y / qn1;
  __syncthreads();

  const int g16 = lane >> 4, m16 = lane & 15;
  float qh[8];
  #pragma unroll
  for (int d = 0; d < 8; ++d) qh[d] = qh_s[W][m16 * 8 + d];
  int rounds = (total + 3) >> 2;
  for (int r = 0; r < rounds; ++r) {
    int cc = r * 4 + g16;
    bool valid = cc < total;
    float2 ce = valid ? list[W][cc] : make_float2(0.f, __int_as_float(0));
    int sidx = __float_as_int(ce.y);
    float4 sa = *reinterpret_cast<const float4*>(supports + (size_t)sidx * 128 + m16 * 8);
    float4 sb = *reinterpret_cast<const float4*>(supports + (size_t)sidx * 128 + m16 * 8 + 4);
    float sv[8] = {sa.x, sa.y, sa.z, sa.w, sb.x, sb.y, sb.z, sb.w};
    double ss = 0.0, dt = 0.0;
    #pragma unroll
    for (int d = 0; d < 8; ++d) {
      ss += (double)sv[d] * sv[d];
      dt += (double)qh[d] * sv[d];
    }
    #pragma unroll
    for (int o = 1; o < 16; o <<= 1) {
      ss += __shfl_xor(ss, o);
      dt += __shfl_xor(dt, o);
    }
    if (m16 == 0 && valid) {
      float sn1 = fmaxf((float)sqrt(ss), 1e-12f);
      refd[W][cc] = make_float2((float)(1.0 - dt / (double)sn1), ce.y);
    }
  }
  __syncthreads();

  float dv = (lane < total) ? refd[W][lane].x : 3.0e38f;
  unsigned di = (lane < total) ? (unsigned)__float_as_int(refd[W][lane].y) : 0xFFFFFFFFu;
  bitonic64(dv, di, lane);  // ascending (d, idx): lanes 0..15 = top-16

  float wv = (lane < 16) ? 1.0f / (dv + 1e-8f) : 0.0f;
  float wsum = wv;
  #pragma unroll
  for (int o = 1; o < 64; o <<= 1) wsum += __shfl_xor(wsum, o);
  float acc[8];
  #pragma unroll
  for (int t = 0; t < 8; ++t) acc[t] = 0.f;
  if (lane < 16) {
    float wn = wv / wsum;
    const float* tp = targets + (size_t)di * 8;
    #pragma unroll
    for (int t = 0; t < 8; ++t) acc[t] = wn * tp[t];
  }
  #pragma unroll
  for (int o = 1; o < 16; o <<= 1) {
    #pragma unroll
    for (int t = 0; t < 8; ++t) acc[t] += __shfl_xor(acc[t], o);
  }
  if (lane == 0) {
    #pragma unroll
    for (int t = 0; t < 8; ++t) out[(size_t)q * 8 + t] = acc[t];
  }
}

extern "C" void kernel_launch(void* const* d_in, const int* in_sizes, int n_in,
                              void* d_out, int out_size, void* d_ws, size_t ws_size,
                              hipStream_t stream) {
  const float* query = (const float*)d_in[0];
  const float* supports = (const float*)d_in[1];
  const float* targets = (const float*)d_in[2];
  float* out = (float*)d_out;
  const int D = 128;
  const int B = in_sizes[0] / D;   // 2048
  const int N = in_sizes[1] / D;   // 100000

  char* ws = (char*)d_ws;
  size_t off = 0;
  ushort* sn = (ushort*)(ws + off); off += (size_t)N * D * 2;
  off = (off + 255) & ~(size_t)255;
  ushort* qn = (ushort*)(ws + off); off += (size_t)B * D * 2;
  off = (off + 255) & ~(size_t)255;
  ushort* cm = (ushort*)(ws + off); off += (size_t)B * NGS * 2;        // 26.2MB
  off = (off + 255) & ~(size_t)255;
  float* thr = (float*)(ws + off); off += (size_t)B * 4;
  off = (off + 255) & ~(size_t)255;
  unsigned* cnt = (unsigned*)(ws + off); off += (size_t)B * 4;
  off = (off + 255) & ~(size_t)255;
  float2* candq = (float2*)(ws + off); off += (size_t)B * QCAP * sizeof(float2);
  if (off > ws_size) return;

  hipLaunchKernelGGL(norm_rows_k, dim3((N + B + 3) / 4), dim3(256), 0, stream,
                     supports, query, sn, qn, N, B);
  int nblk = (B / BQ) * NSLICES;  // 1024
  hipLaunchKernelGGL(pass1_k, dim3(nblk), dim3(256), 0, stream, qn, sn, cm, N);
  hipLaunchKernelGGL(thr_k, dim3(B / 4), dim3(256), 0, stream, cm, thr, cnt);
  hipLaunchKernelGGL(pass2_k, dim3(nblk), dim3(256), 0, stream, qn, sn, cm, thr, cnt, candq, N);
  hipLaunchKernelGGL(merge_refine_k, dim3(B / 4), dim3(256), 0, stream, query, supports, targets, cnt, candq, out);
}

// Round 13
// 186.600 us; speedup vs baseline: 1.2634x; 1.0084x over previous
//
#include <hip/hip_runtime.h>

// SHGR kNN head: cosine distance, top-16, inverse-distance weighted target average.
// B=2048, N=100000, D=128, T=8, k=16.
//
// Pipeline (5 dispatches):
//   1. norm_rows_k (fused): L2-normalize supports AND queries -> bf16 in ws.
//   2. pass1_k: transposed bf16 MFMA (D[support][query]); per-(query,16-support
//      sub) max -> cm (bf16 down-rounded, [q/4][gs][q%4]). Counted-vmcnt
//      pipeline (isolated R10 technique on R12's proven geometry): raw
//      s_barrier + vmcnt(8) keeps the 4-load prefetch in flight across the
//      barrier instead of __syncthreads' full vmcnt(0) drain.
//   3. thr_k: thr[q] = (16th-largest of 6400 sub-maxes) - 0.013 margin; also
//      zeroes cnt[q]. 4 queries/block.
//   4. pass2_k [R9-proven]: visit hit subs only (stored max >= thr), batch 4 ->
//      staged tile, recompute scores (bitwise-identical MFMA), emit >= thr to
//      per-query global list (cap 64).
//   5. merge_refine_k: 4 queries/block; exact (f64) refine ALL ~27 cands,
//      bitonic top-16 -> weights -> gather targets -> out.
//
// NOTE (R7): update_dpp row_ror gave wrong submaxes on gfx950 -> shfl_xor only.
// NOTE (R10/R11): pass1 is wave-count-bound; 256thr/4-wave blocks, grid 1024 =
// 4 blk/CU beats 5-blk exact-fit and 2-wave variants.

#define NSLICES 64
#define CN 64
#define BQ 128
#define NSUB 100                 // subs per slice = 25 chunks * 4
#define NGS (NSLICES * NSUB)     // 6400 subs per query
#define QCAP 64                  // per-query candidate list; E=27, P(>64)~1e-9
#define THR_MARGIN 0.013f

typedef __bf16 bf16x8 __attribute__((ext_vector_type(8)));
typedef float f32x4 __attribute__((ext_vector_type(4)));

__device__ __forceinline__ ushort f2bf_rne(float f) {
  unsigned u = __float_as_uint(f);
  return (ushort)((u + 0x7FFFu + ((u >> 16) & 1u)) >> 16);
}
// round toward -inf in bf16 (stored max <= true max)
__device__ __forceinline__ ushort f2bf_down(float f) {
  unsigned u = __float_as_uint(f);
  return (ushort)((u >> 16) + (u >> 31));
}
__device__ __forceinline__ unsigned bf2key(ushort b) {
  return (unsigned)(b ^ ((b & 0x8000u) ? 0xFFFFu : 0x8000u));
}

// Full-wave bitonic sort, ascending in (v, i) lexicographic.
__device__ __forceinline__ void bitonic64(float& v, unsigned& i, int lane) {
  #pragma unroll
  for (int k = 2; k <= 64; k <<= 1) {
    #pragma unroll
    for (int j = k >> 1; j > 0; j >>= 1) {
      float pv = __shfl_xor(v, j);
      unsigned pi = (unsigned)__shfl_xor((int)i, j);
      bool up = ((lane & k) == 0);
      bool lower = ((lane & j) == 0);
      bool gt = (v > pv) || (v == pv && i > pi);
      bool keep = (up == lower) ? !gt : gt;
      if (!keep) { v = pv; i = pi; }
    }
  }
}

// Fused: rows [0,N) = supports -> sb; rows [N, N+nq) = queries -> qb.
__global__ __launch_bounds__(256) void norm_rows_k(
    const float* __restrict__ sup, const float* __restrict__ qry,
    ushort* __restrict__ sb, ushort* __restrict__ qb, int N, int nq) {
  int row = blockIdx.x * 4 + (threadIdx.x >> 6);
  int lane = threadIdx.x & 63;
  if (row >= N + nq) return;
  const float* src = (row < N) ? (sup + (size_t)row * 128)
                               : (qry + (size_t)(row - N) * 128);
  ushort* dst = (row < N) ? (sb + (size_t)row * 128)
                          : (qb + (size_t)(row - N) * 128);
  float2 v = *reinterpret_cast<const float2*>(src + lane * 2);
  float ss = v.x * v.x + v.y * v.y;
  #pragma unroll
  for (int o = 1; o < 64; o <<= 1) ss += __shfl_xor(ss, o);
  float inv = 1.0f / fmaxf(sqrtf(ss), 1e-12f);
  ushort2 h = make_ushort2(f2bf_rne(v.x * inv), f2bf_rne(v.y * inv));
  *reinterpret_cast<ushort2*>(dst + lane * 2) = h;
}

// Stage 64x128 bf16 chunk: linear LDS dest + inverse-swizzled global source.
// Exactly 4 global_load_lds per wave (vmcnt += 4).
__device__ __forceinline__ void stage_lin(const ushort* __restrict__ sn,
                                          ushort* dst, int cb, int s1, int tid) {
  #pragma unroll
  for (int r = 0; r < 4; ++r) {
    int o = (r << 12) + tid * 16;
    int row = o >> 8;
    int dj = (o >> 4) & 15;
    int sj = dj ^ (row & 7);
    int srow = min(cb + row, s1 - 1);
    __builtin_amdgcn_global_load_lds(
        (const unsigned int*)(sn + (size_t)srow * 128 + sj * 8),
        (unsigned int*)(dst + (o >> 1)), 16, 0, 0);
  }
}

// Stage a gathered batch of 4 sub-chunks (16 rows each) from slist.
__device__ __forceinline__ void stage_list(const ushort* __restrict__ sn,
                                           ushort* dst, const ushort* slist_b,
                                           int s0, int s1, int tid) {
  #pragma unroll
  for (int r = 0; r < 4; ++r) {
    int o = (r << 12) + tid * 16;
    int row = o >> 8;
    int dj = (o >> 4) & 15;
    int sj = dj ^ (row & 7);
    int sub = slist_b[row >> 4];
    int lrow = (sub == 0xFFFF) ? 0 : sub * 16 + (row & 15);
    int srow = min(s0 + lrow, s1 - 1);
    __builtin_amdgcn_global_load_lds(
        (const unsigned int*)(sn + (size_t)srow * 128 + sj * 8),
        (unsigned int*)(dst + (o >> 1)), 16, 0, 0);
  }
}

// Pass 1: sub-chunk maxes. 1024 blocks XCD-decoded (8 slices/XCD).
// Transposed MFMA: D[row=support][col=query]; lane holds 4 supports x 1 query.
// Counted-vmcnt pipeline: prefetch loads stay in flight across raw barriers.
__global__ __launch_bounds__(256, 4) void pass1_k(
    const ushort* __restrict__ qn, const ushort* __restrict__ sn,
    ushort* __restrict__ cm, int N) {
  __shared__ ushort st[2][CN * 128];
  const int tid = threadIdx.x;
  const int w = tid >> 6, lane = tid & 63, g = lane >> 4, m = lane & 15;
  const int L = blockIdx.x;             // 1024 = 8 xcd * (16 qtile * 8 slice)
  const int xcd = L & 7, i6 = L >> 3;
  const int qtile = i6 & 15;
  const int slice = (xcd << 3) | (i6 >> 4);
  const int qbase = qtile * BQ;
  const int SLICE = (N + NSLICES - 1) / NSLICES;  // 1563
  const int s0 = slice * SLICE;
  const int s1 = min(N, s0 + SLICE);
  const int nch = (s1 - s0 + CN - 1) / CN;  // 25 (24 for last slice)

  stage_lin(sn, &st[0][0], s0, s1, tid);

  // Query fragments (B operand): k = 32*t + 8*g + e, col = m.
  bf16x8 afr[2][4];
  #pragma unroll
  for (int jt = 0; jt < 2; ++jt) {
    int qrow = qbase + w * 32 + jt * 16 + m;
    #pragma unroll
    for (int t = 0; t < 4; ++t)
      afr[jt][t] = *reinterpret_cast<const bf16x8*>(qn + (size_t)qrow * 128 + t * 32 + g * 8);
  }
  // drain chunk-0 prefetch + afr loads; release all waves
  asm volatile("s_waitcnt vmcnt(0)" ::: "memory");
  __builtin_amdgcn_s_barrier();
  __builtin_amdgcn_sched_barrier(0);

  int buf = 0;
  for (int ch = 0; ch < nch; ++ch) {
    const int cb = s0 + ch * CN;
    const bool has_next = (ch + 1 < nch);
    if (has_next) stage_lin(sn, &st[buf ^ 1][0], cb + CN, s1, tid);  // 4 loads in flight
    const ushort* stc = &st[buf][0];
    const bool lastch = (ch == nch - 1);
    #pragma unroll
    for (int ct = 0; ct < 4; ++ct) {
      const int srow = ct * 16 + m;     // A-operand row = support (lane m)
      f32x4 a0 = {0.f, 0.f, 0.f, 0.f}, a1 = {0.f, 0.f, 0.f, 0.f};
      #pragma unroll
      for (int t = 0; t < 4; ++t) {
        int cj = (4 * t + g) ^ (srow & 7);
        bf16x8 sfr = *reinterpret_cast<const bf16x8*>(&stc[srow * 128 + cj * 8]);
        a0 = __builtin_amdgcn_mfma_f32_16x16x32_bf16(sfr, afr[0][t], a0, 0, 0, 0);
        a1 = __builtin_amdgcn_mfma_f32_16x16x32_bf16(sfr, afr[1][t], a1, 0, 0, 0);
      }
      // mask invalid supports (D rows: support = cb + ct*16 + g*4 + e)
      if (lastch) {
        int si = cb + ct * 16 + g * 4;
        #pragma unroll
        for (int e = 0; e < 4; ++e) {
          if (si + e >= s1) { a0[e] = -3.0e38f; a1[e] = -3.0e38f; }
        }
      }
      // in-register max over 4 supports, then across the 4 g-groups
      float v0 = fmaxf(fmaxf(a0[0], a0[1]), fmaxf(a0[2], a0[3]));
      float v1 = fmaxf(fmaxf(a1[0], a1[1]), fmaxf(a1[2], a1[3]));
      v0 = fmaxf(v0, __shfl_xor(v0, 16));
      v0 = fmaxf(v0, __shfl_xor(v0, 32));
      v1 = fmaxf(v1, __shfl_xor(v1, 16));
      v1 = fmaxf(v1, __shfl_xor(v1, 32));
      // pack 4 queries' bf16 submaxes -> 8B store on lanes (g==0, m%4==0)
      unsigned u0 = (unsigned)f2bf_down(v0);
      unsigned u1 = (unsigned)f2bf_down(v1);
      unsigned w0 = u0 | ((unsigned)__shfl_xor((int)u0, 1) << 16);
      unsigned w1 = u1 | ((unsigned)__shfl_xor((int)u1, 1) << 16);
      unsigned x0 = (unsigned)__shfl_xor((int)w0, 2);
      unsigned x1 = (unsigned)__shfl_xor((int)w1, 2);
      if (g == 0 && (m & 3) == 0) {     // 4 lanes always active -> uniform issue
        int gs = slice * NSUB + ch * 4 + ct;
        int q0 = qbase + w * 32 + m;       // jt=0 queries q0..q0+3 (q0%4==0)
        int q1 = q0 + 16;                  // jt=1
        *reinterpret_cast<uint2*>(cm + ((size_t)(q0 >> 2) * NGS + gs) * 4) =
            make_uint2(w0, x0);
        *reinterpret_cast<uint2*>(cm + ((size_t)(q1 >> 2) * NGS + gs) * 4) =
            make_uint2(w1, x1);
      }
    }
    if (has_next) {
      // vmcnt queue (in-order): [L(next)=4 loads, S(this)=8 stores].
      // vmcnt(8) <=> the 4 prefetch loads retired; stores may stay in flight.
      // ds_reads were consumed by MFMAs before this point (compiler lgkm
      // waits), so no lgkmcnt needed. Barrier then releases buf^1 for reading
      // and buf for the next iteration's prefetch overwrite.
      asm volatile("s_waitcnt vmcnt(8)" ::: "memory");
      __builtin_amdgcn_s_barrier();
      __builtin_amdgcn_sched_barrier(0);
    }
    buf ^= 1;
  }

  // fill unwritten tail subs (nch < 25 on the last slice) with bf16 -inf
  const int miss = NSUB - nch * 4;
  for (int idx = tid; idx < miss * BQ; idx += 256) {
    int sub = nch * 4 + idx / BQ;
    int q = qbase + (idx % BQ);
    cm[((size_t)(q >> 2) * NGS + (size_t)(slice * NSUB + sub)) * 4 + (q & 3)] = 0xFF80;
  }
}

// thr[q] = 16th-largest of the 6400 sub-maxes, minus margin; zero cnt[q].
// 4 queries per 256-thread block (one per wave) -> q-group shares cache lines.
__global__ __launch_bounds__(256) void thr_k(const ushort* __restrict__ cm,
                                             float* __restrict__ thr,
                                             unsigned* __restrict__ cnt) {
  const int q = blockIdx.x * 4 + (threadIdx.x >> 6);
  const int lane = threadIdx.x & 63;
  const size_t base = (size_t)(q >> 2) * NGS * 4 + (q & 3);
  unsigned keys[NGS / 128];
  #pragma unroll
  for (int j = 0; j < NGS / 128; ++j) {
    unsigned k0 = bf2key(cm[base + (size_t)(lane + 128 * j) * 4]);
    unsigned k1 = bf2key(cm[base + (size_t)(lane + 64 + 128 * j) * 4]);
    keys[j] = k0 | (k1 << 16);
  }
  unsigned res = 0;
  for (int b = 15; b >= 0; --b) {
    unsigned t = res | (1u << b);
    int c = 0;
    #pragma unroll
    for (int j = 0; j < NGS / 128; ++j)
      c += (int)((keys[j] & 0xFFFFu) >= t) + (int)((keys[j] >> 16) >= t);
    #pragma unroll
    for (int o = 1; o < 64; o <<= 1) c += __shfl_xor(c, o);
    if (c >= 16) res = t;
  }
  if (lane == 0) {
    ushort b16 = (ushort)((res & 0x8000u) ? (res ^ 0x8000u) : (res ^ 0xFFFFu));
    thr[q] = __uint_as_float((unsigned)b16 << 16) - THR_MARGIN;
    cnt[q] = 0;
  }
}

// Pass 2 [R9-proven]: visit only hit subs (stored max >= thr), 4 per batch.
// Transposed MFMA: lane holds 4 supports x 1 query; thr per lane hoisted.
__global__ __launch_bounds__(256, 4) void pass2_k(
    const ushort* __restrict__ qn, const ushort* __restrict__ sn,
    const ushort* __restrict__ cm, const float* __restrict__ thr,
    unsigned* __restrict__ cnt, float2* __restrict__ candq, int N) {
  __shared__ ushort st[2][CN * 128];
  __shared__ float thr_l[BQ];
  __shared__ unsigned char hit[NSUB];
  __shared__ ushort slist[NSUB + 4];
  __shared__ int nhit_s;

  const int tid = threadIdx.x;
  const int w = tid >> 6, lane = tid & 63, g = lane >> 4, m = lane & 15;
  const int L = blockIdx.x;
  const int xcd = L & 7, i6 = L >> 3;
  const int qtile = i6 & 15;
  const int slice = (xcd << 3) | (i6 >> 4);
  const int qbase = qtile * BQ;
  const int SLICE = (N + NSLICES - 1) / NSLICES;
  const int s0 = slice * SLICE;
  const int s1 = min(N, s0 + SLICE);
  const int slen = s1 - s0;

  if (tid < BQ) thr_l[tid] = thr[qbase + tid];
  if (tid < NSUB) hit[tid] = 0;
  __syncthreads();

  // hit scan: thread (q = tid&127, parity = tid>>7) covers s = 2j+parity
  {
    int q = qbase + (tid & 127);
    int sh = tid >> 7;
    float tq = thr_l[tid & 127];
    size_t base = (size_t)(q >> 2) * NGS * 4 + (q & 3);
    for (int j = 0; j < NSUB / 2; ++j) {
      int s = 2 * j + sh;
      ushort b = cm[base + (size_t)(slice * NSUB + s) * 4];
      if (__uint_as_float((unsigned)b << 16) >= tq) hit[s] = 1;
    }
  }
  __syncthreads();
  // compact hit subs (wave 0)
  if (tid < 64) {
    int total = 0;
    #pragma unroll
    for (int r = 0; r < 2; ++r) {
      int idx = r * 64 + tid;
      bool f = (idx < NSUB) && hit[idx];
      unsigned long long bm = __ballot(f);
      int pos = total + __popcll(bm & ((1ull << tid) - 1ull));
      if (f) slist[pos] = (ushort)idx;
      total += __popcll(bm);
    }
    if (tid == 0) {
      nhit_s = total;
      #pragma unroll
      for (int p = 0; p < 4; ++p) slist[total + p] = 0xFFFF;
    }
  }
  __syncthreads();
  const int nhit = nhit_s;
  if (nhit == 0) return;
  const int nb = (nhit + 3) >> 2;

  bf16x8 afr[2][4];
  #pragma unroll
  for (int jt = 0; jt < 2; ++jt) {
    int qrow = qbase + w * 32 + jt * 16 + m;
    #pragma unroll
    for (int t = 0; t < 4; ++t)
      afr[jt][t] = *reinterpret_cast<const bf16x8*>(qn + (size_t)qrow * 128 + t * 32 + g * 8);
  }
  const float thrq0 = thr_l[w * 32 + m];        // query of jt=0 (lane m)
  const float thrq1 = thr_l[w * 32 + 16 + m];   // query of jt=1

  stage_list(sn, &st[0][0], &slist[0], s0, s1, tid);
  __syncthreads();

  int buf = 0;
  for (int b = 0; b < nb; ++b) {
    if (b + 1 < nb) stage_list(sn, &st[buf ^ 1][0], &slist[(b + 1) * 4], s0, s1, tid);
    const ushort* stc = &st[buf][0];
    #pragma unroll
    for (int ct = 0; ct < 4; ++ct) {
      const int srow = ct * 16 + m;
      f32x4 a0 = {0.f, 0.f, 0.f, 0.f}, a1 = {0.f, 0.f, 0.f, 0.f};
      #pragma unroll
      for (int t = 0; t < 4; ++t) {
        int cj = (4 * t + g) ^ (srow & 7);
        bf16x8 sfr = *reinterpret_cast<const bf16x8*>(&stc[srow * 128 + cj * 8]);
        a0 = __builtin_amdgcn_mfma_f32_16x16x32_bf16(sfr, afr[0][t], a0, 0, 0, 0);
        a1 = __builtin_amdgcn_mfma_f32_16x16x32_bf16(sfr, afr[1][t], a1, 0, 0, 0);
      }
      int sub = slist[b * 4 + ct];
      if (sub != 0xFFFF) {
        int li0 = sub * 16 + g * 4;    // slice-local support of e=0 (D row)
        bool h0[4], h1[4];
        bool any = false;
        #pragma unroll
        for (int e = 0; e < 4; ++e) {
          bool ok = (li0 + e) < slen;
          h0[e] = ok && (a0[e] >= thrq0);
          h1[e] = ok && (a1[e] >= thrq1);
          any = any || h0[e] || h1[e];
        }
        if (__any(any)) {
          #pragma unroll
          for (int e = 0; e < 4; ++e) {
            if (h0[e]) {
              int q = qbase + w * 32 + m;
              unsigned p = atomicAdd(&cnt[q], 1u);
              if (p < (unsigned)QCAP)
                candq[(size_t)q * QCAP + p] =
                    make_float2(a0[e], __int_as_float(s0 + li0 + e));
            }
            if (h1[e]) {
              int q = qbase + w * 32 + 16 + m;
              unsigned p = atomicAdd(&cnt[q], 1u);
              if (p < (unsigned)QCAP)
                candq[(size_t)q * QCAP + p] =
                    make_float2(a1[e], __int_as_float(s0 + li0 + e));
            }
          }
        }
      }
    }
    __syncthreads();
    buf ^= 1;
  }
}

// 4 queries per 256-thread block (one wave each): gather ~27 candidates,
// exact (f64) refine ALL, bitonic top-16 (tie: lower idx) -> weights -> out.
__global__ __launch_bounds__(256) void merge_refine_k(
    const float* __restrict__ query, const float* __restrict__ supports,
    const float* __restrict__ targets, const unsigned* __restrict__ cnt,
    const float2* __restrict__ candq, float* __restrict__ out) {
  const int W = threadIdx.x >> 6;
  const int q = blockIdx.x * 4 + W;
  const int lane = threadIdx.x & 63;
  __shared__ float qh_s[4][128];
  __shared__ float2 list[4][QCAP];
  __shared__ float2 refd[4][QCAP];

  int total = min((int)cnt[q], QCAP);
  if (lane < total) list[W][lane] = candq[(size_t)q * QCAP + lane];

  float2 qv = *reinterpret_cast<const float2*>(query + (size_t)q * 128 + lane * 2);
  double qss = (double)qv.x * qv.x + (double)qv.y * qv.y;
  #pragma unroll
  for (int o = 1; o < 64; o <<= 1) qss += __shfl_xor(qss, o);
  float qn1 = fmaxf((float)sqrt(qss), 1e-12f);
  qh_s[W][lane * 2] = qv.x / qn1;
  qh_s[W][lane * 2 + 1] = qv.y / qn1;
  __syncthreads();

  const int g16 = lane >> 4, m16 = lane & 15;
  float qh[8];
  #pragma unroll
  for (int d = 0; d < 8; ++d) qh[d] = qh_s[W][m16 * 8 + d];
  int rounds = (total + 3) >> 2;
  for (int r = 0; r < rounds; ++r) {
    int cc = r * 4 + g16;
    bool valid = cc < total;
    float2 ce = valid ? list[W][cc] : make_float2(0.f, __int_as_float(0));
    int sidx = __float_as_int(ce.y);
    float4 sa = *reinterpret_cast<const float4*>(supports + (size_t)sidx * 128 + m16 * 8);
    float4 sb = *reinterpret_cast<const float4*>(supports + (size_t)sidx * 128 + m16 * 8 + 4);
    float sv[8] = {sa.x, sa.y, sa.z, sa.w, sb.x, sb.y, sb.z, sb.w};
    double ss = 0.0, dt = 0.0;
    #pragma unroll
    for (int d = 0; d < 8; ++d) {
      ss += (double)sv[d] * sv[d];
      dt += (double)qh[d] * sv[d];
    }
    #pragma unroll
    for (int o = 1; o < 16; o <<= 1) {
      ss += __shfl_xor(ss, o);
      dt += __shfl_xor(dt, o);
    }
    if (m16 == 0 && valid) {
      float sn1 = fmaxf((float)sqrt(ss), 1e-12f);
      refd[W][cc] = make_float2((float)(1.0 - dt / (double)sn1), ce.y);
    }
  }
  __syncthreads();

  float dv = (lane < total) ? refd[W][lane].x : 3.0e38f;
  unsigned di = (lane < total) ? (unsigned)__float_as_int(refd[W][lane].y) : 0xFFFFFFFFu;
  bitonic64(dv, di, lane);  // ascending (d, idx): lanes 0..15 = top-16

  float wv = (lane < 16) ? 1.0f / (dv + 1e-8f) : 0.0f;
  float wsum = wv;
  #pragma unroll
  for (int o = 1; o < 64; o <<= 1) wsum += __shfl_xor(wsum, o);
  float acc[8];
  #pragma unroll
  for (int t = 0; t < 8; ++t) acc[t] = 0.f;
  if (lane < 16) {
    float wn = wv / wsum;
    const float* tp = targets + (size_t)di * 8;
    #pragma unroll
    for (int t = 0; t < 8; ++t) acc[t] = wn * tp[t];
  }
  #pragma unroll
  for (int o = 1; o < 16; o <<= 1) {
    #pragma unroll
    for (int t = 0; t < 8; ++t) acc[t] += __shfl_xor(acc[t], o);
  }
  if (lane == 0) {
    #pragma unroll
    for (int t = 0; t < 8; ++t) out[(size_t)q * 8 + t] = acc[t];
  }
}

extern "C" void kernel_launch(void* const* d_in, const int* in_sizes, int n_in,
                              void* d_out, int out_size, void* d_ws, size_t ws_size,
                              hipStream_t stream) {
  const float* query = (const float*)d_in[0];
  const float* supports = (const float*)d_in[1];
  const float* targets = (const float*)d_in[2];
  float* out = (float*)d_out;
  const int D = 128;
  const int B = in_sizes[0] / D;   // 2048
  const int N = in_sizes[1] / D;   // 100000

  char* ws = (char*)d_ws;
  size_t off = 0;
  ushort* sn = (ushort*)(ws + off); off += (size_t)N * D * 2;
  off = (off + 255) & ~(size_t)255;
  ushort* qn = (ushort*)(ws + off); off += (size_t)B * D * 2;
  off = (off + 255) & ~(size_t)255;
  ushort* cm = (ushort*)(ws + off); off += (size_t)B * NGS * 2;        // 26.2MB
  off = (off + 255) & ~(size_t)255;
  float* thr = (float*)(ws + off); off += (size_t)B * 4;
  off = (off + 255) & ~(size_t)255;
  unsigned* cnt = (unsigned*)(ws + off); off += (size_t)B * 4;
  off = (off + 255) & ~(size_t)255;
  float2* candq = (float2*)(ws + off); off += (size_t)B * QCAP * sizeof(float2);
  if (off > ws_size) return;

  hipLaunchKernelGGL(norm_rows_k, dim3((N + B + 3) / 4), dim3(256), 0, stream,
                     supports, query, sn, qn, N, B);
  int nblk = (B / BQ) * NSLICES;  // 1024
  hipLaunchKernelGGL(pass1_k, dim3(nblk), dim3(256), 0, stream, qn, sn, cm, N);
  hipLaunchKernelGGL(thr_k, dim3(B / 4), dim3(256), 0, stream, cm, thr, cnt);
  hipLaunchKernelGGL(pass2_k, dim3(nblk), dim3(256), 0, stream, qn, sn, cm, thr, cnt, candq, N);
  hipLaunchKernelGGL(merge_refine_k, dim3(B / 4), dim3(256), 0, stream, query, supports, targets, cnt, candq, out);
}

// Round 14
// 174.192 us; speedup vs baseline: 1.3534x; 1.0712x over previous
//
#include <hip/hip_runtime.h>

// SHGR kNN head: cosine distance, top-16, inverse-distance weighted target average.
// B=2048, N=100000, D=128, T=8, k=16.
//
// Pipeline (5 dispatches):
//   1. norm_rows_k (fused): L2-normalize supports AND queries -> bf16 in ws.
//   2. pass1_k: transposed 32x32x16 bf16 MFMA (D[support][query]; lane holds 16
//      supports x 1 query) -> per-(query,32-support sub) max is 15 in-reg fmax
//      + ONE shfl_xor(32) (was 32 LDS-pipe shuffles/chunk with 16x16). cm
//      (bf16 down-rounded, [q/4][gs][q%4]).
//   3. thr_k: thr[q] = (16th-largest of 3200 sub-maxes) - 0.013 margin; zeroes
//      cnt[q]. [16 subs >= t => 16 distinct supports >= t => t <= s16; margin
//      covers bf16 score error (<=2.5e-3) 5x; E[cands] ~ 27/query]
//   4. pass2_k: visit hit subs only (stored max >= thr), 2 subs per staged
//      64-row tile, recompute scores (bitwise-identical MFMA), emit >= thr to
//      per-query global list (cap 64).
//   5. merge_refine_k: 4 queries/block; exact (f64) refine ALL ~27 cands,
//      bitonic top-16 -> weights -> gather targets -> out.
//
// NOTE (R7): update_dpp row_ror gave wrong submaxes on gfx950 -> shfl_xor only.
// NOTE (R10/R11): pass1 wave-count-bound at 16x16; grid 1024 = 4 blk/CU.
// NOTE (R13): counted-vmcnt null -> plain __syncthreads (loads hide under LDS).
// LDS swizzle: ^(row&15) both in stage (source-permute, linear dest) and read.

#define NSLICES 64
#define CN 64
#define BQ 128
#define NSUB 50                  // subs per slice = 25 chunks * 2 (32-support subs)
#define NGS (NSLICES * NSUB)     // 3200 subs per query
#define QCAP 64                  // per-query candidate list; E=27, P(>64)~1e-9
#define THR_MARGIN 0.013f

typedef __bf16 bf16x8 __attribute__((ext_vector_type(8)));
typedef float f32x16 __attribute__((ext_vector_type(16)));

__device__ __forceinline__ ushort f2bf_rne(float f) {
  unsigned u = __float_as_uint(f);
  return (ushort)((u + 0x7FFFu + ((u >> 16) & 1u)) >> 16);
}
// round toward -inf in bf16 (stored max <= true max)
__device__ __forceinline__ ushort f2bf_down(float f) {
  unsigned u = __float_as_uint(f);
  return (ushort)((u >> 16) + (u >> 31));
}
__device__ __forceinline__ unsigned bf2key(ushort b) {
  return (unsigned)(b ^ ((b & 0x8000u) ? 0xFFFFu : 0x8000u));
}

// Full-wave bitonic sort, ascending in (v, i) lexicographic.
__device__ __forceinline__ void bitonic64(float& v, unsigned& i, int lane) {
  #pragma unroll
  for (int k = 2; k <= 64; k <<= 1) {
    #pragma unroll
    for (int j = k >> 1; j > 0; j >>= 1) {
      float pv = __shfl_xor(v, j);
      unsigned pi = (unsigned)__shfl_xor((int)i, j);
      bool up = ((lane & k) == 0);
      bool lower = ((lane & j) == 0);
      bool gt = (v > pv) || (v == pv && i > pi);
      bool keep = (up == lower) ? !gt : gt;
      if (!keep) { v = pv; i = pi; }
    }
  }
}

// Fused: rows [0,N) = supports -> sb; rows [N, N+nq) = queries -> qb.
__global__ __launch_bounds__(256) void norm_rows_k(
    const float* __restrict__ sup, const float* __restrict__ qry,
    ushort* __restrict__ sb, ushort* __restrict__ qb, int N, int nq) {
  int row = blockIdx.x * 4 + (threadIdx.x >> 6);
  int lane = threadIdx.x & 63;
  if (row >= N + nq) return;
  const float* src = (row < N) ? (sup + (size_t)row * 128)
                               : (qry + (size_t)(row - N) * 128);
  ushort* dst = (row < N) ? (sb + (size_t)row * 128)
                          : (qb + (size_t)(row - N) * 128);
  float2 v = *reinterpret_cast<const float2*>(src + lane * 2);
  float ss = v.x * v.x + v.y * v.y;
  #pragma unroll
  for (int o = 1; o < 64; o <<= 1) ss += __shfl_xor(ss, o);
  float inv = 1.0f / fmaxf(sqrtf(ss), 1e-12f);
  ushort2 h = make_ushort2(f2bf_rne(v.x * inv), f2bf_rne(v.y * inv));
  *reinterpret_cast<ushort2*>(dst + lane * 2) = h;
}

// Stage 64x128 bf16 chunk: linear LDS dest + inverse-swizzled (^row&15) source.
__device__ __forceinline__ void stage_lin(const ushort* __restrict__ sn,
                                          ushort* dst, int cb, int s1, int tid) {
  #pragma unroll
  for (int r = 0; r < 4; ++r) {
    int o = (r << 12) + tid * 16;
    int row = o >> 8;
    int dj = (o >> 4) & 15;
    int sj = dj ^ (row & 15);
    int srow = min(cb + row, s1 - 1);
    __builtin_amdgcn_global_load_lds(
        (const unsigned int*)(sn + (size_t)srow * 128 + sj * 8),
        (unsigned int*)(dst + (o >> 1)), 16, 0, 0);
  }
}

// Stage a gathered batch of 2 subs (32 rows each) from slist.
__device__ __forceinline__ void stage_list(const ushort* __restrict__ sn,
                                           ushort* dst, const ushort* slist_b,
                                           int s0, int s1, int tid) {
  #pragma unroll
  for (int r = 0; r < 4; ++r) {
    int o = (r << 12) + tid * 16;
    int row = o >> 8;
    int dj = (o >> 4) & 15;
    int sj = dj ^ (row & 15);
    int sub = slist_b[row >> 5];
    int lrow = (sub == 0xFFFF) ? 0 : sub * 32 + (row & 31);
    int srow = min(s0 + lrow, s1 - 1);
    __builtin_amdgcn_global_load_lds(
        (const unsigned int*)(sn + (size_t)srow * 128 + sj * 8),
        (unsigned int*)(dst + (o >> 1)), 16, 0, 0);
  }
}

// Pass 1: 32-support sub maxes. 1024 blocks XCD-decoded (8 slices/XCD).
// 32x32x16 MFMA, D[row=support][col=query]: lane = query (lane&31) x 16 rows.
__global__ __launch_bounds__(256, 4) void pass1_k(
    const ushort* __restrict__ qn, const ushort* __restrict__ sn,
    ushort* __restrict__ cm, int N) {
  __shared__ ushort st[2][CN * 128];
  const int tid = threadIdx.x;
  const int w = tid >> 6, lane = tid & 63;
  const int q32 = lane & 31, half = lane >> 5;
  const int L = blockIdx.x;             // 1024 = 8 xcd * (16 qtile * 8 slice)
  const int xcd = L & 7, i6 = L >> 3;
  const int qtile = i6 & 15;
  const int slice = (xcd << 3) | (i6 >> 4);
  const int qbase = qtile * BQ;
  const int SLICE = (N + NSLICES - 1) / NSLICES;  // 1563
  const int s0 = slice * SLICE;
  const int s1 = min(N, s0 + SLICE);
  const int nch = (s1 - s0 + CN - 1) / CN;  // 25 (24 for last slice)

  stage_lin(sn, &st[0][0], s0, s1, tid);

  // Query fragments (B operand): col = lane&31, k = half*8 + e per 16-k step.
  bf16x8 afr[8];
  {
    const int qrow = qbase + w * 32 + q32;
    #pragma unroll
    for (int t = 0; t < 8; ++t)
      afr[t] = *reinterpret_cast<const bf16x8*>(qn + (size_t)qrow * 128 + t * 16 + half * 8);
  }
  __syncthreads();

  int buf = 0;
  for (int ch = 0; ch < nch; ++ch) {
    const int cb = s0 + ch * CN;
    if (ch + 1 < nch) stage_lin(sn, &st[buf ^ 1][0], cb + CN, s1, tid);
    const ushort* stc = &st[buf][0];
    const bool lastch = (ch == nch - 1);

    f32x16 a0 = {0.f}, a1 = {0.f};
    #pragma unroll
    for (int r = 1; r < 16; ++r) { a0[r] = 0.f; a1[r] = 0.f; }
    const int r0 = q32;                  // A row within tile = lane&31
    #pragma unroll
    for (int t = 0; t < 8; ++t) {
      int jb = t * 2 + half;             // 16B block in row
      int cj0 = jb ^ (r0 & 15);
      int cj1 = jb ^ ((r0 + 32) & 15);   // == cj0 (rows differ by 32)
      bf16x8 s0 = *reinterpret_cast<const bf16x8*>(&stc[r0 * 128 + cj0 * 8]);
      bf16x8 s1 = *reinterpret_cast<const bf16x8*>(&stc[(r0 + 32) * 128 + cj1 * 8]);
      a0 = __builtin_amdgcn_mfma_f32_32x32x16_bf16(s0, afr[t], a0, 0, 0, 0);
      a1 = __builtin_amdgcn_mfma_f32_32x32x16_bf16(s1, afr[t], a1, 0, 0, 0);
    }
    // per-lane max over 16 supports (rows), masking invalid on last chunk
    float v0 = -3.0e38f, v1 = -3.0e38f;
    if (lastch) {
      #pragma unroll
      for (int r = 0; r < 16; ++r) {
        int row = (r & 3) + 8 * (r >> 2) + (half << 2);
        if (cb + row < s1) v0 = fmaxf(v0, a0[r]);
        if (cb + 32 + row < s1) v1 = fmaxf(v1, a1[r]);
      }
    } else {
      #pragma unroll
      for (int r = 0; r < 16; ++r) {
        v0 = fmaxf(v0, a0[r]);
        v1 = fmaxf(v1, a1[r]);
      }
    }
    // other 16 rows live in the opposite 32-lane half
    v0 = fmaxf(v0, __shfl_xor(v0, 32));
    v1 = fmaxf(v1, __shfl_xor(v1, 32));
    if (lane < 32) {                     // 32 lanes store 2B each
      int q = qbase + w * 32 + q32;
      size_t e0 = ((size_t)(q >> 2) * NGS + slice * NSUB + ch * 2) * 4 + (q & 3);
      cm[e0] = f2bf_down(v0);
      cm[e0 + 4] = f2bf_down(v1);        // gs+1 -> +4 elements
    }
    __syncthreads();
    buf ^= 1;
  }

  // fill unwritten tail subs (nch < 25 on the last slice) with bf16 -inf
  const int miss = NSUB - nch * 2;
  for (int idx = tid; idx < miss * BQ; idx += 256) {
    int sub = nch * 2 + idx / BQ;
    int q = qbase + (idx % BQ);
    cm[((size_t)(q >> 2) * NGS + (size_t)(slice * NSUB + sub)) * 4 + (q & 3)] = 0xFF80;
  }
}

// thr[q] = 16th-largest of the 3200 sub-maxes, minus margin; zero cnt[q].
// 4 queries per 256-thread block (one per wave).
__global__ __launch_bounds__(256) void thr_k(const ushort* __restrict__ cm,
                                             float* __restrict__ thr,
                                             unsigned* __restrict__ cnt) {
  const int q = blockIdx.x * 4 + (threadIdx.x >> 6);
  const int lane = threadIdx.x & 63;
  const size_t base = (size_t)(q >> 2) * NGS * 4 + (q & 3);
  unsigned keys[NGS / 128];
  #pragma unroll
  for (int j = 0; j < NGS / 128; ++j) {
    unsigned k0 = bf2key(cm[base + (size_t)(lane + 128 * j) * 4]);
    unsigned k1 = bf2key(cm[base + (size_t)(lane + 64 + 128 * j) * 4]);
    keys[j] = k0 | (k1 << 16);
  }
  unsigned res = 0;
  for (int b = 15; b >= 0; --b) {
    unsigned t = res | (1u << b);
    int c = 0;
    #pragma unroll
    for (int j = 0; j < NGS / 128; ++j)
      c += (int)((keys[j] & 0xFFFFu) >= t) + (int)((keys[j] >> 16) >= t);
    #pragma unroll
    for (int o = 1; o < 64; o <<= 1) c += __shfl_xor(c, o);
    if (c >= 16) res = t;
  }
  if (lane == 0) {
    ushort b16 = (ushort)((res & 0x8000u) ? (res ^ 0x8000u) : (res ^ 0xFFFFu));
    thr[q] = __uint_as_float((unsigned)b16 << 16) - THR_MARGIN;
    cnt[q] = 0;
  }
}

// Pass 2: visit only hit subs (stored max >= thr), 2 per staged 64-row batch.
// 32x32x16 MFMA: lane = 1 query x 16 supports; thr per lane hoisted.
__global__ __launch_bounds__(256, 4) void pass2_k(
    const ushort* __restrict__ qn, const ushort* __restrict__ sn,
    const ushort* __restrict__ cm, const float* __restrict__ thr,
    unsigned* __restrict__ cnt, float2* __restrict__ candq, int N) {
  __shared__ ushort st[2][CN * 128];
  __shared__ float thr_l[BQ];
  __shared__ unsigned char hit[NSUB];
  __shared__ ushort slist[NSUB + 2];
  __shared__ int nhit_s;

  const int tid = threadIdx.x;
  const int w = tid >> 6, lane = tid & 63;
  const int q32 = lane & 31, half = lane >> 5;
  const int L = blockIdx.x;
  const int xcd = L & 7, i6 = L >> 3;
  const int qtile = i6 & 15;
  const int slice = (xcd << 3) | (i6 >> 4);
  const int qbase = qtile * BQ;
  const int SLICE = (N + NSLICES - 1) / NSLICES;
  const int s0 = slice * SLICE;
  const int s1 = min(N, s0 + SLICE);
  const int slen = s1 - s0;

  if (tid < BQ) thr_l[tid] = thr[qbase + tid];
  if (tid < NSUB) hit[tid] = 0;
  __syncthreads();

  // hit scan: thread (q = tid&127, parity = tid>>7) covers s = 2j+parity
  {
    int q = qbase + (tid & 127);
    int sh = tid >> 7;
    float tq = thr_l[tid & 127];
    size_t base = (size_t)(q >> 2) * NGS * 4 + (q & 3);
    for (int j = 0; j < NSUB / 2; ++j) {
      int s = 2 * j + sh;
      ushort b = cm[base + (size_t)(slice * NSUB + s) * 4];
      if (__uint_as_float((unsigned)b << 16) >= tq) hit[s] = 1;
    }
  }
  __syncthreads();
  // compact hit subs (wave 0; NSUB <= 64 -> single ballot)
  if (tid < 64) {
    bool f = (tid < NSUB) && hit[tid];
    unsigned long long bm = __ballot(f);
    int pos = __popcll(bm & ((1ull << tid) - 1ull));
    if (f) slist[pos] = (ushort)tid;
    if (tid == 0) {
      int total = __popcll(bm);
      nhit_s = total;
      slist[total] = 0xFFFF;
      slist[total + 1] = 0xFFFF;
    }
  }
  __syncthreads();
  const int nhit = nhit_s;
  if (nhit == 0) return;
  const int nb = (nhit + 1) >> 1;

  bf16x8 afr[8];
  {
    const int qrow = qbase + w * 32 + q32;
    #pragma unroll
    for (int t = 0; t < 8; ++t)
      afr[t] = *reinterpret_cast<const bf16x8*>(qn + (size_t)qrow * 128 + t * 16 + half * 8);
  }
  const float thrq = thr_l[w * 32 + q32];

  stage_list(sn, &st[0][0], &slist[0], s0, s1, tid);
  __syncthreads();

  int buf = 0;
  for (int b = 0; b < nb; ++b) {
    if (b + 1 < nb) stage_list(sn, &st[buf ^ 1][0], &slist[(b + 1) * 2], s0, s1, tid);
    const ushort* stc = &st[buf][0];

    f32x16 a0 = {0.f}, a1 = {0.f};
    #pragma unroll
    for (int r = 1; r < 16; ++r) { a0[r] = 0.f; a1[r] = 0.f; }
    const int r0 = q32;
    #pragma unroll
    for (int t = 0; t < 8; ++t) {
      int jb = t * 2 + half;
      int cj = jb ^ (r0 & 15);
      bf16x8 sf0 = *reinterpret_cast<const bf16x8*>(&stc[r0 * 128 + cj * 8]);
      bf16x8 sf1 = *reinterpret_cast<const bf16x8*>(&stc[(r0 + 32) * 128 + cj * 8]);
      a0 = __builtin_amdgcn_mfma_f32_32x32x16_bf16(sf0, afr[t], a0, 0, 0, 0);
      a1 = __builtin_amdgcn_mfma_f32_32x32x16_bf16(sf1, afr[t], a1, 0, 0, 0);
    }
    const int subA = slist[b * 2], subB = slist[b * 2 + 1];
    const int q = qbase + w * 32 + q32;
    // tile A
    if (subA != 0xFFFF) {
      unsigned hm = 0;
      #pragma unroll
      for (int r = 0; r < 16; ++r) {
        int row = (r & 3) + 8 * (r >> 2) + (half << 2);
        if (subA * 32 + row < slen && a0[r] >= thrq) hm |= 1u << r;
      }
      if (__any(hm != 0u)) {
        #pragma unroll
        for (int r = 0; r < 16; ++r) {
          if (hm & (1u << r)) {
            int row = (r & 3) + 8 * (r >> 2) + (half << 2);
            unsigned p = atomicAdd(&cnt[q], 1u);
            if (p < (unsigned)QCAP)
              candq[(size_t)q * QCAP + p] =
                  make_float2(a0[r], __int_as_float(s0 + subA * 32 + row));
          }
        }
      }
    }
    // tile B
    if (subB != 0xFFFF) {
      unsigned hm = 0;
      #pragma unroll
      for (int r = 0; r < 16; ++r) {
        int row = (r & 3) + 8 * (r >> 2) + (half << 2);
        if (subB * 32 + row < slen && a1[r] >= thrq) hm |= 1u << r;
      }
      if (__any(hm != 0u)) {
        #pragma unroll
        for (int r = 0; r < 16; ++r) {
          if (hm & (1u << r)) {
            int row = (r & 3) + 8 * (r >> 2) + (half << 2);
            unsigned p = atomicAdd(&cnt[q], 1u);
            if (p < (unsigned)QCAP)
              candq[(size_t)q * QCAP + p] =
                  make_float2(a1[r], __int_as_float(s0 + subB * 32 + row));
          }
        }
      }
    }
    __syncthreads();
    buf ^= 1;
  }
}

// 4 queries per 256-thread block (one wave each): gather ~27 candidates,
// exact (f64) refine ALL, bitonic top-16 (tie: lower idx) -> weights -> out.
__global__ __launch_bounds__(256) void merge_refine_k(
    const float* __restrict__ query, const float* __restrict__ supports,
    const float* __restrict__ targets, const unsigned* __restrict__ cnt,
    const float2* __restrict__ candq, float* __restrict__ out) {
  const int W = threadIdx.x >> 6;
  const int q = blockIdx.x * 4 + W;
  const int lane = threadIdx.x & 63;
  __shared__ float qh_s[4][128];
  __shared__ float2 list[4][QCAP];
  __shared__ float2 refd[4][QCAP];

  int total = min((int)cnt[q], QCAP);
  if (lane < total) list[W][lane] = candq[(size_t)q * QCAP + lane];

  float2 qv = *reinterpret_cast<const float2*>(query + (size_t)q * 128 + lane * 2);
  double qss = (double)qv.x * qv.x + (double)qv.y * qv.y;
  #pragma unroll
  for (int o = 1; o < 64; o <<= 1) qss += __shfl_xor(qss, o);
  float qn1 = fmaxf((float)sqrt(qss), 1e-12f);
  qh_s[W][lane * 2] = qv.x / qn1;
  qh_s[W][lane * 2 + 1] = qv.y / qn1;
  __syncthreads();

  const int g16 = lane >> 4, m16 = lane & 15;
  float qh[8];
  #pragma unroll
  for (int d = 0; d < 8; ++d) qh[d] = qh_s[W][m16 * 8 + d];
  int rounds = (total + 3) >> 2;
  for (int r = 0; r < rounds; ++r) {
    int cc = r * 4 + g16;
    bool valid = cc < total;
    float2 ce = valid ? list[W][cc] : make_float2(0.f, __int_as_float(0));
    int sidx = __float_as_int(ce.y);
    float4 sa = *reinterpret_cast<const float4*>(supports + (size_t)sidx * 128 + m16 * 8);
    float4 sb = *reinterpret_cast<const float4*>(supports + (size_t)sidx * 128 + m16 * 8 + 4);
    float sv[8] = {sa.x, sa.y, sa.z, sa.w, sb.x, sb.y, sb.z, sb.w};
    double ss = 0.0, dt = 0.0;
    #pragma unroll
    for (int d = 0; d < 8; ++d) {
      ss += (double)sv[d] * sv[d];
      dt += (double)qh[d] * sv[d];
    }
    #pragma unroll
    for (int o = 1; o < 16; o <<= 1) {
      ss += __shfl_xor(ss, o);
      dt += __shfl_xor(dt, o);
    }
    if (m16 == 0 && valid) {
      float sn1 = fmaxf((float)sqrt(ss), 1e-12f);
      refd[W][cc] = make_float2((float)(1.0 - dt / (double)sn1), ce.y);
    }
  }
  __syncthreads();

  float dv = (lane < total) ? refd[W][lane].x : 3.0e38f;
  unsigned di = (lane < total) ? (unsigned)__float_as_int(refd[W][lane].y) : 0xFFFFFFFFu;
  bitonic64(dv, di, lane);  // ascending (d, idx): lanes 0..15 = top-16

  float wv = (lane < 16) ? 1.0f / (dv + 1e-8f) : 0.0f;
  float wsum = wv;
  #pragma unroll
  for (int o = 1; o < 64; o <<= 1) wsum += __shfl_xor(wsum, o);
  float acc[8];
  #pragma unroll
  for (int t = 0; t < 8; ++t) acc[t] = 0.f;
  if (lane < 16) {
    float wn = wv / wsum;
    const float* tp = targets + (size_t)di * 8;
    #pragma unroll
    for (int t = 0; t < 8; ++t) acc[t] = wn * tp[t];
  }
  #pragma unroll
  for (int o = 1; o < 16; o <<= 1) {
    #pragma unroll
    for (int t = 0; t < 8; ++t) acc[t] += __shfl_xor(acc[t], o);
  }
  if (lane == 0) {
    #pragma unroll
    for (int t = 0; t < 8; ++t) out[(size_t)q * 8 + t] = acc[t];
  }
}

extern "C" void kernel_launch(void* const* d_in, const int* in_sizes, int n_in,
                              void* d_out, int out_size, void* d_ws, size_t ws_size,
                              hipStream_t stream) {
  const float* query = (const float*)d_in[0];
  const float* supports = (const float*)d_in[1];
  const float* targets = (const float*)d_in[2];
  float* out = (float*)d_out;
  const int D = 128;
  const int B = in_sizes[0] / D;   // 2048
  const int N = in_sizes[1] / D;   // 100000

  char* ws = (char*)d_ws;
  size_t off = 0;
  ushort* sn = (ushort*)(ws + off); off += (size_t)N * D * 2;
  off = (off + 255) & ~(size_t)255;
  ushort* qn = (ushort*)(ws + off); off += (size_t)B * D * 2;
  off = (off + 255) & ~(size_t)255;
  ushort* cm = (ushort*)(ws + off); off += (size_t)B * NGS * 2;        // 13.1MB
  off = (off + 255) & ~(size_t)255;
  float* thr = (float*)(ws + off); off += (size_t)B * 4;
  off = (off + 255) & ~(size_t)255;
  unsigned* cnt = (unsigned*)(ws + off); off += (size_t)B * 4;
  off = (off + 255) & ~(size_t)255;
  float2* candq = (float2*)(ws + off); off += (size_t)B * QCAP * sizeof(float2);
  if (off > ws_size) return;

  hipLaunchKernelGGL(norm_rows_k, dim3((N + B + 3) / 4), dim3(256), 0, stream,
                     supports, query, sn, qn, N, B);
  int nblk = (B / BQ) * NSLICES;  // 1024
  hipLaunchKernelGGL(pass1_k, dim3(nblk), dim3(256), 0, stream, qn, sn, cm, N);
  hipLaunchKernelGGL(thr_k, dim3(B / 4), dim3(256), 0, stream, cm, thr, cnt);
  hipLaunchKernelGGL(pass2_k, dim3(nblk), dim3(256), 0, stream, qn, sn, cm, thr, cnt, candq, N);
  hipLaunchKernelGGL(merge_refine_k, dim3(B / 4), dim3(256), 0, stream, query, supports, targets, cnt, candq, out);
}